// Round 3
// baseline (748.223 us; speedup 1.0000x reference)
//
#include <hip/hip_runtime.h>
#include <hip/hip_cooperative_groups.h>

namespace cg = cooperative_groups;

// ---------------------------------------------------------------------------
// PhysNet stack, MI355X.  v4:
//  - ENTIRE S-path + weight prep fused into ONE cooperative kernel (s_all):
//    phase A hist||prep||bias, B 256-block parallel column scan (was 32),
//    C scan+place (1024 thr/block), D gather at 16 waves/CU.
//  - chain kernel unchanged from v3 (87.7 us).
// ---------------------------------------------------------------------------

#define LN2F 0.69314718055994530942f
#define NB 128   // hist chunks

using short8  = __attribute__((ext_vector_type(8))) short;
using float4v = __attribute__((ext_vector_type(4))) float;
typedef const __attribute__((address_space(1))) unsigned int* gas1_t;
typedef __attribute__((address_space(3))) unsigned int* las3_t;

__device__ __forceinline__ float sspf(float x) {
  float ax = fabsf(x);
  return fmaxf(x, 0.0f) + __logf(1.0f + __expf(-ax)) - LN2F;
}

__device__ __forceinline__ unsigned short f2bf(float x) {
  return (unsigned short)((__float_as_uint(x) + 0x8000u) >> 16);  // RTN, <=0.5ulp
}

__device__ __forceinline__ unsigned short f2bf_ne(float x) {  // RTNE for weight prep
  unsigned int u = __float_as_uint(x);
  u += 0x7fffu + ((u >> 16) & 1u);
  return (unsigned short)(u >> 16);
}

__device__ __forceinline__ void dma16(const void* g, void* l) {
  __builtin_amdgcn_global_load_lds((gas1_t)(unsigned long long)g,
                                   (las3_t)(unsigned long long)l, 16, 0, 0);
}

// 16-wave block DMA: 32KB -> 2KB/wave, 16KB -> 1KB/wave
__device__ __forceinline__ void dma32k(const unsigned short* g, unsigned short* l,
                                       int w, int lane) {
  const char* gb = (const char*)g + w * 2048 + lane * 16;
  char* lb = (char*)l + w * 2048;
  dma16(gb, lb);
  dma16(gb + 1024, lb + 1024);
}
__device__ __forceinline__ void dma16k(const unsigned short* g, unsigned short* l,
                                       int w, int lane) {
  dma16((const char*)g + w * 1024 + lane * 16, (char*)l + w * 1024);
}

// ---------------------------------------------------------------------------
// s_all: cooperative fused S-path.
//   A: hist (blocks 0..127) || weight prep (128..207) || bias pack (208..212)
//   B: column scan of H (all 256 blocks, 32 cols each)
//   C: redundant tot-scan -> pos; LDS-atomic place (blocks 0..127)
//   D: gather (all blocks, 32 atoms each, 2 atoms/wave)
// ---------------------------------------------------------------------------
struct SArgs {
  const float* wsrc[80];
  int isgate[80];
  const float* bp[17];
  int bstride[17];
  const float* b_out;
  const int* idx;
  const float* radial;
  unsigned short* Wt;
  float* bias_pack;
  unsigned int* H;
  unsigned int* tot;
  unsigned int* off;
  unsigned int* pairid;
  float* S;
  int P, n2p, C;
};

__global__ __launch_bounds__(1024) void s_all(SArgs K) {
  __shared__ unsigned int shst[8192];   // hist / part / pos (phase-aliased)
  __shared__ unsigned int wtt[16];
  cg::grid_group grid = cg::this_grid();
  const int b = blockIdx.x, tid = threadIdx.x;

  // ---------------- phase A ----------------
  if (b < NB) {
    for (int i = tid; i < 8192; i += 1024) shst[i] = 0;
    __syncthreads();
    int s = b * K.C, e = min(s + K.C, K.n2p);
    for (int i = s + tid; i < e; i += 1024) atomicAdd(&shst[K.idx[i]], 1u);
    __syncthreads();
    for (int i = tid; i < 8192; i += 1024) K.H[(size_t)b * 8192 + i] = shst[i];
  } else if (b < NB + 80) {
    int m = b - NB;
    const float* s = K.wsrc[m];
    unsigned short* d = K.Wt + (size_t)m * 16384;
    if (!K.isgate[m]) {
      for (int it = 0; it < 2; ++it) {
        int q = tid + it * 1024;
        int n = q & 127, j = q >> 7;
        unsigned short tmp[8];
#pragma unroll
        for (int cc = 0; cc < 8; ++cc) tmp[cc] = f2bf_ne(s[(8 * j + cc) * 128 + n]);
        *(uint4*)(d + (n * 16 + (j ^ (n & 15))) * 8) = *(uint4*)tmp;
      }
    } else {
      int n = tid & 127, j = tid >> 7;
      unsigned short tmp[8];
#pragma unroll
      for (int cc = 0; cc < 8; ++cc) tmp[cc] = f2bf_ne(s[(8 * j + cc) * 128 + n]);
      *(uint4*)(d + (n * 8 + (j ^ (n & 7))) * 8) = *(uint4*)tmp;
    }
  } else if (b < NB + 85) {
    int l = b - (NB + 80);
    for (int i = tid; i < 17 * 128; i += 1024) {
      int s = i >> 7;
      K.bias_pack[(size_t)l * 2304 + i] = K.bp[s][l * K.bstride[s] + (i & 127)];
    }
    if (tid == 0) K.bias_pack[(size_t)l * 2304 + 17 * 128] = K.b_out[l];
  }
  __threadfence();
  grid.sync();

  // ---------------- phase B: column scan (32 cols/block, 128 rows) ----------
  {
    unsigned int (*part)[33] = (unsigned int(*)[33])shst;
    const int c = tid & 31, sgm = tid >> 5;         // sgm 0..31, 4 rows each
    const int col = b * 32 + c;
    unsigned int psum = 0;
#pragma unroll
    for (int r = sgm * 4; r < sgm * 4 + 4; ++r)
      psum += K.H[(size_t)r * 8192 + col];
    part[sgm][c] = psum;
    __syncthreads();
    if (tid < 32) {
      unsigned int run = 0;
#pragma unroll
      for (int s2 = 0; s2 < 32; ++s2) {
        unsigned int v = part[s2][tid];
        part[s2][tid] = run;
        run += v;
      }
      K.tot[b * 32 + tid] = run;
    }
    __syncthreads();
    unsigned int run = part[sgm][c];
#pragma unroll
    for (int r = sgm * 4; r < sgm * 4 + 4; ++r) {
      unsigned int v = K.H[(size_t)r * 8192 + col];
      K.H[(size_t)r * 8192 + col] = run;
      run += v;
    }
  }
  __threadfence();
  grid.sync();

  // ---------------- phase C: tot-scan -> pos; place ----------
  if (b < NB) {
    unsigned int loc[8], ssum = 0;
#pragma unroll
    for (int i = 0; i < 8; ++i) { loc[i] = K.tot[tid * 8 + i]; ssum += loc[i]; }
    unsigned int v = ssum;
    const int lane = tid & 63, wv2 = tid >> 6;
#pragma unroll
    for (int o = 1; o < 64; o <<= 1) {
      unsigned int u = __shfl_up(v, o, 64);
      if (lane >= o) v += u;
    }
    if (lane == 63) wtt[wv2] = v;
    __syncthreads();
    unsigned int base2 = 0;
    for (int k = 0; k < wv2; ++k) base2 += wtt[k];
    unsigned int excl = base2 + v - ssum;
#pragma unroll
    for (int i = 0; i < 8; ++i) {
      unsigned int a = tid * 8 + i;
      if (b == 0) K.off[a] = excl;
      shst[a] = excl + K.H[(size_t)b * 8192 + a];
      excl += loc[i];
    }
    if (b == 0 && tid == 1023) K.off[8192] = excl;
    __syncthreads();
    int s3 = b * K.C, e3 = min(s3 + K.C, K.n2p);
    for (int i = s3 + tid; i < e3; i += 1024) {
      int a = K.idx[i];
      unsigned int p = atomicAdd(&shst[a], 1u);
      K.pairid[p] = (i >= K.P) ? (unsigned int)(i - K.P) : (unsigned int)i;
    }
  }
  __threadfence();
  grid.sync();

  // ---------------- phase D: gather (2 atoms per wave) ----------
  {
    const int wv = tid >> 6, lane = tid & 63;
    const int grp = lane >> 4, l16v = lane & 15;
#pragma unroll 1
    for (int j2 = 0; j2 < 2; ++j2) {
      int a = b * 32 + wv * 2 + j2;
      unsigned int bb = K.off[a], ee = K.off[a + 1];
      float4v acc = {0.f, 0.f, 0.f, 0.f};
      for (unsigned int base = bb; base < ee; base += 32) {
        unsigned int pp[8];
#pragma unroll
        for (int k = 0; k < 8; ++k) {
          unsigned int j = base + k * 4 + grp;
          pp[k] = K.pairid[j < ee ? j : bb];     // clamped: always valid
        }
        float4v vv[8];
#pragma unroll
        for (int k = 0; k < 8; ++k)
          vv[k] = *(const float4v*)(K.radial + (size_t)pp[k] * 64 + l16v * 4);
#pragma unroll
        for (int k = 0; k < 8; ++k) {
          unsigned int j = base + k * 4 + grp;
          if (j < ee) acc += vv[k];
        }
      }
#pragma unroll
      for (int o = 16; o < 64; o <<= 1) {
#pragma unroll
        for (int cc = 0; cc < 4; ++cc) acc[cc] += __shfl_xor(acc[cc], o, 64);
      }
      if (grp == 0)
        *(float4v*)(K.S + (size_t)a * 64 + l16v * 4) = acc;
    }
  }
}

// ---------------------------------------------------------------------------
// Chain v3 (unchanged): 256 blocks x 1024 threads (16 waves), 1 block/CU.
// ---------------------------------------------------------------------------
struct ChainArgs {
  const float* feat_in;
  const float* S;
  const unsigned short* wt;      // 80 slots x 16384 shorts
  const float* bias_pack;        // 5 x 2304 floats
  float* feat_out;
  float* energy;
};

#define MFMA_ __builtin_amdgcn_mfma_f32_16x16x32_bf16

#define G128(AP, SP, ACC) { \
  short8 a0_ = *(const short8*)(aB + (AP)*4352); \
  short8 a1_ = *(const short8*)(aB + (AP)*4352 + 32); \
  short8 a2_ = *(const short8*)(aB + (AP)*4352 + 64); \
  short8 a3_ = *(const short8*)(aB + (AP)*4352 + 96); \
  ACC = MFMA_(a0_, *(const short8*)(b0 + (SP)*16384), ACC, 0, 0, 0); \
  ACC = MFMA_(a1_, *(const short8*)(b1 + (SP)*16384), ACC, 0, 0, 0); \
  ACC = MFMA_(a2_, *(const short8*)(b2 + (SP)*16384), ACC, 0, 0, 0); \
  ACC = MFMA_(a3_, *(const short8*)(b3 + (SP)*16384), ACC, 0, 0, 0); }

#define WSSPM(AP, V) { \
  wB[(AP)*4352]       = f2bf(sspf((V)[0])); \
  wB[(AP)*4352 + 136] = f2bf(sspf((V)[1])); \
  wB[(AP)*4352 + 272] = f2bf(sspf((V)[2])); \
  wB[(AP)*4352 + 408] = f2bf(sspf((V)[3])); }

#define MODBODY(S0) { \
  const float* bl = &sB[(S0)][0]; \
  /* G1: gate(sG) + W_J  [reads A0, swb[S0]] */ \
  dma32k(wtp + 2*16384, swb[(S0)^1], w, lane); \
  gG = Z; \
  { short8 s0_ = *(const short8*)(aS); short8 s1_ = *(const short8*)(aS + 32); \
    gG = MFMA_(s0_, *(const short8*)(g0), gG, 0, 0, 0); \
    gG = MFMA_(s1_, *(const short8*)(g1), gG, 0, 0, 0); } \
  fm = Z; G128(0, (S0), fm); \
  { float bv = bl[col0]; \
    for (int r = 0; r < 4; ++r) fm[r] = sspf(fm[r] + bv); } \
  __syncthreads(); \
  /* G2: W_I -> proto -> A1 ; prefetch next gate */ \
  dma32k(wtp + 3*16384, swb[(S0)], w, lane); \
  if (l < 4) dma16k(wtp + 16*16384, sG, w, lane); \
  t4 = Z; G128(0, (S0)^1, t4); \
  { float bv = bl[128 + col0]; \
    for (int r = 0; r < 4; ++r) xf[r] = fm[r]*gG[r] + sspf(t4[r] + bv); } \
  WSSPM(1, xf); \
  __syncthreads(); \
  /* G3..G8: ri x3 */ \
  dma32k(wtp + 4*16384, swb[(S0)^1], w, lane); \
  t4 = Z; G128(1, (S0), t4); \
  { float bv = bl[2*128 + col0]; for (int r = 0; r < 4; ++r) t4[r] += bv; } \
  WSSPM(0, t4); __syncthreads(); \
  dma32k(wtp + 5*16384, swb[(S0)], w, lane); \
  t4 = Z; G128(0, (S0)^1, t4); \
  { float bv = bl[3*128 + col0]; for (int r = 0; r < 4; ++r) xf[r] += t4[r] + bv; } \
  WSSPM(1, xf); __syncthreads(); \
  dma32k(wtp + 6*16384, swb[(S0)^1], w, lane); \
  t4 = Z; G128(1, (S0), t4); \
  { float bv = bl[4*128 + col0]; for (int r = 0; r < 4; ++r) t4[r] += bv; } \
  WSSPM(0, t4); __syncthreads(); \
  dma32k(wtp + 7*16384, swb[(S0)], w, lane); \
  t4 = Z; G128(0, (S0)^1, t4); \
  { float bv = bl[5*128 + col0]; for (int r = 0; r < 4; ++r) xf[r] += t4[r] + bv; } \
  WSSPM(1, xf); __syncthreads(); \
  dma32k(wtp + 8*16384, swb[(S0)^1], w, lane); \
  t4 = Z; G128(1, (S0), t4); \
  { float bv = bl[6*128 + col0]; for (int r = 0; r < 4; ++r) t4[r] += bv; } \
  WSSPM(0, t4); __syncthreads(); \
  dma32k(wtp + 9*16384, swb[(S0)], w, lane); \
  t4 = Z; G128(0, (S0)^1, t4); \
  { float bv = bl[7*128 + col0]; for (int r = 0; r < 4; ++r) xf[r] += t4[r] + bv; } \
  WSSPM(1, xf); __syncthreads(); \
  /* G9: W_int */ \
  dma32k(wtp + 10*16384, swb[(S0)^1], w, lane); \
  t4 = Z; G128(1, (S0), t4); \
  { float bv = bl[8*128 + col0]; float gv = bl[15*128 + col0]; \
    for (int r = 0; r < 4; ++r) xf[r] = ff[r]*gv + t4[r] + bv; } \
  WSSPM(0, xf); __syncthreads(); \
  /* G10..G13: ra x2 */ \
  dma32k(wtp + 11*16384, swb[(S0)], w, lane); \
  t4 = Z; G128(0, (S0)^1, t4); \
  { float bv = bl[9*128 + col0]; for (int r = 0; r < 4; ++r) t4[r] += bv; } \
  WSSPM(1, t4); __syncthreads(); \
  dma32k(wtp + 12*16384, swb[(S0)^1], w, lane); \
  t4 = Z; G128(1, (S0), t4); \
  { float bv = bl[10*128 + col0]; for (int r = 0; r < 4; ++r) xf[r] += t4[r] + bv; } \
  WSSPM(0, xf); __syncthreads(); \
  dma32k(wtp + 13*16384, swb[(S0)], w, lane); \
  t4 = Z; G128(0, (S0)^1, t4); \
  { float bv = bl[11*128 + col0]; for (int r = 0; r < 4; ++r) t4[r] += bv; } \
  WSSPM(1, t4); __syncthreads(); \
  dma32k(wtp + 14*16384, swb[(S0)^1], w, lane); \
  if (l < 4 && w < 9) \
    dma16((const char*)A.bias_pack + (size_t)(l + 1) * 9216 + w * 1024 + lane * 16, \
          (char*)&sB[(S0)^1][0] + w * 1024); \
  t4 = Z; G128(1, (S0), t4); \
  { float bv = bl[12*128 + col0]; for (int r = 0; r < 4; ++r) xf[r] += t4[r] + bv; } \
  WSSPM(0, xf); __syncthreads(); \
  ff = xf; \
  if (l == 4) { \
    for (int r = 0; r < 4; ++r) \
      A.feat_out[(size_t)(row0 + arow + quad*4 + r) * 128 + col0] = xf[r]; \
  } \
  /* G14: ro1 */ \
  dma32k(wtp + 15*16384, swb[(S0)], w, lane); \
  t4 = Z; G128(0, (S0)^1, t4); \
  { float bv = bl[13*128 + col0]; for (int r = 0; r < 4; ++r) t4[r] += bv; } \
  WSSPM(1, t4); __syncthreads(); \
  /* G15: ro2 + energy */ \
  if (l < 4) dma32k(wtp + 17*16384, swb[(S0)^1], w, lane); \
  t4 = Z; G128(1, (S0), t4); \
  { float bv = bl[14*128 + col0]; float wv = bl[16*128 + col0]; \
    p0 += sspf(xf[0] + t4[0] + bv) * wv; \
    p1 += sspf(xf[1] + t4[1] + bv) * wv; \
    p2 += sspf(xf[2] + t4[2] + bv) * wv; \
    p3 += sspf(xf[3] + t4[3] + bv) * wv; } \
  bsum += bl[17*128]; \
  __syncthreads(); }

__global__ __launch_bounds__(1024, 4) void chain_kernel(ChainArgs A) {
  __shared__ __align__(16) unsigned short swb[2][16384];   // 64 KB weight dbuf
  __shared__ __align__(16) unsigned short sG[8192];        // 16 KB gate
  __shared__ __align__(16) unsigned short sA[2][32 * 136]; // 17.4 KB
  __shared__ __align__(16) unsigned short sS[32 * 72];     // 4.5 KB
  __shared__ __align__(16) float sB[2][2304];              // 18.4 KB bias dbuf
  __shared__ float sE[32];

  const int tid  = threadIdx.x;
  const int row0 = blockIdx.x * 32;
  const int lane = tid & 63;
  const int w    = tid >> 6;       // 0..15
  const int g    = w >> 3;         // row group 0..1
  const int c    = w & 7;          // col 16-chunk 0..7
  const int l16  = lane & 15;
  const int quad = lane >> 4;
  const int arow = 16 * g;
  const int col0 = 16 * c + l16;
  const int l8   = l16 & 7;

  const unsigned short* aB = &sA[0][0] + (arow + l16) * 136 + quad * 8;
  unsigned short*       wB = &sA[0][0] + (arow + quad * 4) * 136 + col0;
  const unsigned short* b0 = &swb[0][0] + col0 * 128 + (((quad + 0) ^ l16) * 8);
  const unsigned short* b1 = &swb[0][0] + col0 * 128 + (((quad + 4) ^ l16) * 8);
  const unsigned short* b2 = &swb[0][0] + col0 * 128 + (((quad + 8) ^ l16) * 8);
  const unsigned short* b3 = &swb[0][0] + col0 * 128 + (((quad + 12) ^ l16) * 8);
  const unsigned short* aS = &sS[0] + (arow + l16) * 72 + quad * 8;
  const unsigned short* g0 = &sG[0] + col0 * 64 + (((quad + 0) ^ l8) * 8);
  const unsigned short* g1 = &sG[0] + col0 * 64 + (((quad + 4) ^ l8) * 8);

  dma16k(A.wt, sG, w, lane);
  dma32k(A.wt + 16384, swb[0], w, lane);
  if (w < 9)
    dma16((const char*)A.bias_pack + w * 1024 + lane * 16, (char*)&sB[0][0] + w * 1024);

  for (int i = tid; i < 32 * 64; i += 1024) {
    int r = i >> 6, k = i & 63;
    sS[r * 72 + k] = f2bf(A.S[(size_t)(row0 + r) * 64 + k]);
  }
  for (int i = tid; i < 32 * 128; i += 1024) {
    int r = i >> 7, k = i & 127;
    sA[0][r * 136 + k] = f2bf(sspf(A.feat_in[(size_t)(row0 + r) * 128 + k]));
  }
  float4v ff;
#pragma unroll
  for (int r = 0; r < 4; ++r)
    ff[r] = A.feat_in[(size_t)(row0 + arow + quad * 4 + r) * 128 + col0];
  if (tid < 32) sE[tid] = 0.0f;
  __syncthreads();

  const float4v Z = {0.f, 0.f, 0.f, 0.f};
  float4v gG, fm, xf, t4;
  float p0 = 0.f, p1 = 0.f, p2 = 0.f, p3 = 0.f, bsum = 0.f;

#pragma unroll 1
  for (int l = 0; l < 5; ++l) {
    const unsigned short* wtp = A.wt + (size_t)l * 16 * 16384;
    if ((l & 1) == 0) MODBODY(0) else MODBODY(1)
  }

#pragma unroll
  for (int o = 1; o < 16; o <<= 1) {
    p0 += __shfl_xor(p0, o, 64);
    p1 += __shfl_xor(p1, o, 64);
    p2 += __shfl_xor(p2, o, 64);
    p3 += __shfl_xor(p3, o, 64);
  }
  if (l16 == 0) {
    atomicAdd(&sE[arow + quad * 4 + 0], p0);
    atomicAdd(&sE[arow + quad * 4 + 1], p1);
    atomicAdd(&sE[arow + quad * 4 + 2], p2);
    atomicAdd(&sE[arow + quad * 4 + 3], p3);
  }
  __syncthreads();
  if (tid < 32) A.energy[row0 + tid] = sE[tid] + bsum;
}

// ---------------------------------------------------------------------------
extern "C" void kernel_launch(void* const* d_in, const int* in_sizes, int n_in,
                              void* d_out, int out_size, void* d_ws, size_t ws_size,
                              hipStream_t stream) {
  const float* features = (const float*)d_in[1];
  const float* radial   = (const float*)d_in[2];
  const int*   idx12    = (const int*)  d_in[3];
  const float* W_I    = (const float*)d_in[4];
  const float* b_I    = (const float*)d_in[5];
  const float* W_J    = (const float*)d_in[6];
  const float* b_J    = (const float*)d_in[7];
  const float* W_gate = (const float*)d_in[8];
  const float* gvec   = (const float*)d_in[9];
  const float* W_int  = (const float*)d_in[10];
  const float* b_int  = (const float*)d_in[11];
  const float* ri_W1  = (const float*)d_in[12];
  const float* ri_b1  = (const float*)d_in[13];
  const float* ri_W2  = (const float*)d_in[14];
  const float* ri_b2  = (const float*)d_in[15];
  const float* ra_W1  = (const float*)d_in[16];
  const float* ra_b1  = (const float*)d_in[17];
  const float* ra_W2  = (const float*)d_in[18];
  const float* ra_b2  = (const float*)d_in[19];
  const float* ro_W1  = (const float*)d_in[20];
  const float* ro_b1  = (const float*)d_in[21];
  const float* ro_W2  = (const float*)d_in[22];
  const float* ro_b2  = (const float*)d_in[23];
  const float* W_out  = (const float*)d_in[24];
  const float* b_out  = (const float*)d_in[25];

  const int N = in_sizes[1] / 128;   // 8192
  const int P = in_sizes[3] / 2;     // 400000
  const int L = in_sizes[25];        // 5
  const int n2p = 2 * P;
  const int C = (n2p + NB - 1) / NB;

  // ws layout: S | bias_pack | Wt | H | tot | off | pairid
  float* S = (float*)d_ws;
  float* bias_pack = S + (size_t)N * 64;
  unsigned short* Wt = (unsigned short*)(bias_pack + 5 * 2304);
  unsigned int* H      = (unsigned int*)(Wt + (size_t)80 * 16384);
  unsigned int* tot    = H + (size_t)NB * 8192;
  unsigned int* off    = tot + N;
  unsigned int* pairid = off + N + 4;

  SArgs sa;
  for (int l = 0; l < L; ++l) {
    const float* fx[16] = {
      W_gate + l * 8192,
      W_J + l * 16384, W_I + l * 16384,
      ri_W1 + (l * 3 + 0) * 16384, ri_W2 + (l * 3 + 0) * 16384,
      ri_W1 + (l * 3 + 1) * 16384, ri_W2 + (l * 3 + 1) * 16384,
      ri_W1 + (l * 3 + 2) * 16384, ri_W2 + (l * 3 + 2) * 16384,
      W_int + l * 16384,
      ra_W1 + (l * 2 + 0) * 16384, ra_W2 + (l * 2 + 0) * 16384,
      ra_W1 + (l * 2 + 1) * 16384, ra_W2 + (l * 2 + 1) * 16384,
      ro_W1 + l * 16384, ro_W2 + l * 16384 };
    for (int t = 0; t < 16; ++t) { sa.wsrc[l * 16 + t] = fx[t]; sa.isgate[l * 16 + t] = (t == 0); }
  }
  const float* bp[17] = { b_J, b_I,
    ri_b1, ri_b2, ri_b1 + 128, ri_b2 + 128, ri_b1 + 256, ri_b2 + 256,
    b_int, ra_b1, ra_b2, ra_b1 + 128, ra_b2 + 128, ro_b1, ro_b2, gvec, W_out };
  int st[17] = {128,128, 384,384,384,384,384,384, 128, 256,256,256,256, 128,128,128,128};
  for (int q = 0; q < 17; ++q) { sa.bp[q] = bp[q]; sa.bstride[q] = st[q]; }
  sa.b_out = b_out;
  sa.idx = idx12; sa.radial = radial;
  sa.Wt = Wt; sa.bias_pack = bias_pack;
  sa.H = H; sa.tot = tot; sa.off = off; sa.pairid = pairid; sa.S = S;
  sa.P = P; sa.n2p = n2p; sa.C = C;

  void* kargs[] = { (void*)&sa };
  hipLaunchCooperativeKernel((const void*)s_all, dim3(256), dim3(1024),
                             kargs, 0, stream);

  ChainArgs ca;
  ca.feat_in   = features;
  ca.S         = S;
  ca.wt        = Wt;
  ca.bias_pack = bias_pack;
  ca.energy    = (float*)d_out;
  ca.feat_out  = (float*)d_out + N;
  chain_kernel<<<N / 32, 1024, 0, stream>>>(ca);
}

// Round 4
// 351.569 us; speedup vs baseline: 2.1282x; 2.1282x over previous
//
#include <hip/hip_runtime.h>

// ---------------------------------------------------------------------------
// PhysNet stack, MI355X.  v5:
//  - S-path reverted to v3 split kernels (coop s_all was latency-bound, 462us).
//  - chain: weights are wave-private -> loaded DIRECTLY into registers
//    (4x dwordx4/wave/stage, prefetched 1 stage ahead, W[2][4] dbuf) from a
//    fragment-ordered weight pack. No global_load_lds left -> barriers are
//    raw s_barrier + lgkmcnt(0) (no vmcnt(0) drain; weight prefetch spans
//    barriers). LDS only holds A-tile + S-tile (~22KB). Biases = per-stage
//    wave-private dword loads. 14 barriers/module (G1+G2 share a phase).
// ---------------------------------------------------------------------------

#define LN2F 0.69314718055994530942f
#define NB 128   // sort blocks

using short8  = __attribute__((ext_vector_type(8))) short;
using float4v = __attribute__((ext_vector_type(4))) float;

__device__ __forceinline__ float sspf(float x) {
  float ax = fabsf(x);
  return fmaxf(x, 0.0f) + __logf(1.0f + __expf(-ax)) - LN2F;
}

__device__ __forceinline__ unsigned short f2bf(float x) {
  return (unsigned short)((__float_as_uint(x) + 0x8000u) >> 16);  // RTN, <=0.5ulp
}

__device__ __forceinline__ unsigned short f2bf_ne(float x) {  // RTNE for weight prep
  unsigned int u = __float_as_uint(x);
  u += 0x7fffu + ((u >> 16) & 1u);
  return (unsigned short)(u >> 16);
}

// ---------------------------------------------------------------------------
// K1: fused prep_weights (blocks 0..79) + pack_bias (80..84) + hist (85..212)
// Weight pack layout (non-gate slot, 16384 shorts):
//   chunk(c,m,lane): offset c*2048 + m*512 + lane*8; lane=(quad,l16);
//   holds W[k = 8*(4m+quad)+kk][n = 16c+l16], kk=0..7.   (gate: c*1024+m*512)
// ---------------------------------------------------------------------------
struct K1Args {
  const float* wsrc[80];
  int isgate[80];
  const float* bp[17];
  int bstride[17];
  const float* b_out;
  const int* idx;
  unsigned short* Wt;
  float* bias_pack;
  unsigned int* H;
  int n2p, C;
};

__global__ __launch_bounds__(256) void k1_prep(K1Args K) {
  __shared__ unsigned int h[8192];
  int b = blockIdx.x, tid = threadIdx.x;
  if (b < 80) {
    const float* s = K.wsrc[b];
    unsigned short* d = K.Wt + (size_t)b * 16384;
    if (!K.isgate[b]) {
      for (int it = 0; it < 8; ++it) {
        int id = tid + it * 256;
        int lane = id & 63, mm = (id >> 6) & 3, c8 = id >> 8;
        int l16 = lane & 15, quad = lane >> 4;
        int n = 16 * c8 + l16, k0 = 8 * (4 * mm + quad);
        unsigned short tmp[8];
#pragma unroll
        for (int cc = 0; cc < 8; ++cc) tmp[cc] = f2bf_ne(s[(k0 + cc) * 128 + n]);
        *(uint4*)(d + c8 * 2048 + mm * 512 + lane * 8) = *(uint4*)tmp;
      }
    } else {
      for (int it = 0; it < 4; ++it) {
        int id = tid + it * 256;                 // 0..1023
        int lane = id & 63, mm = (id >> 6) & 1, c8 = id >> 7;
        int l16 = lane & 15, quad = lane >> 4;
        int n = 16 * c8 + l16, k0 = 8 * (4 * mm + quad);
        unsigned short tmp[8];
#pragma unroll
        for (int cc = 0; cc < 8; ++cc) tmp[cc] = f2bf_ne(s[(k0 + cc) * 128 + n]);
        *(uint4*)(d + c8 * 1024 + mm * 512 + lane * 8) = *(uint4*)tmp;
      }
    }
  } else if (b < 85) {
    int l = b - 80;
    for (int i = tid; i < 17 * 128; i += 256) {
      int s = i >> 7;
      K.bias_pack[(size_t)l * 2304 + i] = K.bp[s][l * K.bstride[s] + (i & 127)];
    }
    if (tid == 0) K.bias_pack[(size_t)l * 2304 + 17 * 128] = K.b_out[l];
  } else {
    int blk = b - 85;
    for (int i = tid; i < 8192; i += 256) h[i] = 0;
    __syncthreads();
    int s = blk * K.C, e = min(s + K.C, K.n2p);
    for (int i = s + tid; i < e; i += 256) atomicAdd(&h[K.idx[i]], 1u);
    __syncthreads();
    for (int i = tid; i < 8192; i += 256) K.H[(size_t)blk * 8192 + i] = h[i];
  }
}

__global__ __launch_bounds__(256) void col_scan(unsigned int* __restrict__ H,
                                                unsigned int* __restrict__ tot) {
  int a = blockIdx.x * 256 + threadIdx.x;
  unsigned int run = 0;
  for (int b = 0; b < NB; ++b) {
    unsigned int v = H[(size_t)b * 8192 + a];
    H[(size_t)b * 8192 + a] = run;
    run += v;
  }
  tot[a] = run;
}

// place with inline scan of tot (each block redundantly; block 0 publishes off)
__global__ __launch_bounds__(256) void place_pass(const int* __restrict__ idx,
                                                  const unsigned int* __restrict__ H,
                                                  const unsigned int* __restrict__ tot,
                                                  unsigned int* __restrict__ off_out,
                                                  unsigned int* __restrict__ pairid,
                                                  int P, int C) {
  __shared__ unsigned int pos[8192];
  __shared__ unsigned int wt4[4];
  int b = blockIdx.x, tid = threadIdx.x;
  unsigned int local[32], s = 0;
#pragma unroll
  for (int i = 0; i < 32; ++i) { local[i] = tot[tid * 32 + i]; s += local[i]; }
  unsigned int v = s;
  int lane = tid & 63, wv = tid >> 6;
#pragma unroll
  for (int o = 1; o < 64; o <<= 1) {
    unsigned int u = __shfl_up(v, o, 64);
    if (lane >= o) v += u;
  }
  if (lane == 63) wt4[wv] = v;
  __syncthreads();
  unsigned int base = 0;
  for (int k = 0; k < wv; ++k) base += wt4[k];
  unsigned int excl = base + v - s;
#pragma unroll
  for (int i = 0; i < 32; ++i) {
    pos[tid * 32 + i] = excl;
    if (b == 0) off_out[tid * 32 + i] = excl;
    excl += local[i];
  }
  if (b == 0 && tid == 255) off_out[8192] = excl;
  __syncthreads();
  for (int i = tid; i < 8192; i += 256) pos[i] += H[(size_t)b * 8192 + i];
  __syncthreads();
  int n2p = 2 * P;
  int s2 = b * C, e2 = min(s2 + C, n2p);
  for (int i = s2 + tid; i < e2; i += 256) {
    int a = idx[i];
    unsigned int p = atomicAdd(&pos[a], 1u);
    pairid[p] = (i >= P) ? (unsigned int)(i - P) : (unsigned int)i;
  }
}

// Gather: 16-lane group reads a full 256B radial row via dwordx4
__global__ __launch_bounds__(256) void gather_kernel(const float* __restrict__ radial,
                                                     const unsigned int* __restrict__ off,
                                                     const unsigned int* __restrict__ pairid,
                                                     float* __restrict__ S) {
  __shared__ float4v red[3][16];
  int a = blockIdx.x;
  int lane = threadIdx.x & 63, w = threadIdx.x >> 6;
  int grp = lane >> 4, l16v = lane & 15;
  unsigned int b = off[a], e = off[a + 1];
  float4v acc = {0.f, 0.f, 0.f, 0.f};
  for (unsigned int base = b; base < e; base += 128) {
    unsigned int pp[8];
#pragma unroll
    for (int k = 0; k < 8; ++k) {
      unsigned int j = base + k * 16 + w * 4 + grp;
      pp[k] = pairid[j < e ? j : b];          // clamped: always valid
    }
    float4v vv[8];
#pragma unroll
    for (int k = 0; k < 8; ++k)
      vv[k] = *(const float4v*)(radial + (size_t)pp[k] * 64 + l16v * 4);
#pragma unroll
    for (int k = 0; k < 8; ++k) {
      unsigned int j = base + k * 16 + w * 4 + grp;
      if (j < e) acc += vv[k];
    }
  }
#pragma unroll
  for (int o = 16; o < 64; o <<= 1) {
#pragma unroll
    for (int cc = 0; cc < 4; ++cc) acc[cc] += __shfl_xor(acc[cc], o, 64);
  }
  if (w > 0 && grp == 0) red[w - 1][l16v] = acc;
  __syncthreads();
  if (w == 0 && grp == 0) {
    acc += red[0][l16v];
    acc += red[1][l16v];
    acc += red[2][l16v];
    *(float4v*)(S + (size_t)a * 64 + l16v * 4) = acc;
  }
}

// ---------------------------------------------------------------------------
// Chain v5: 256 blocks x 1024 threads (16 waves), 1 block/CU.
// Weights in registers (W[2][4] short8 dbuf, prefetch dist 1). Raw barriers.
// ---------------------------------------------------------------------------
struct ChainArgs {
  const float* feat_in;
  const float* S;
  const unsigned short* wt;      // 80 slots x 16384 shorts (fragment order)
  const float* bias_pack;        // 5 x 2304 floats
  float* feat_out;
  float* energy;
};

#define MFMA_ __builtin_amdgcn_mfma_f32_16x16x32_bf16

#define BAR() { __builtin_amdgcn_sched_barrier(0); \
  asm volatile("s_waitcnt lgkmcnt(0)" ::: "memory"); \
  __builtin_amdgcn_s_barrier(); \
  __builtin_amdgcn_sched_barrier(0); }

#define LDW(WP, sp) { \
  const unsigned short* wp_ = (sp) + woff; \
  W[WP][0] = *(const short8*)(wp_); \
  W[WP][1] = *(const short8*)(wp_ + 512); \
  W[WP][2] = *(const short8*)(wp_ + 1024); \
  W[WP][3] = *(const short8*)(wp_ + 1536); }

#define G128R(AP, WP, ACC) { \
  short8 a0_ = *(const short8*)(aB + (AP)*4352); \
  short8 a1_ = *(const short8*)(aB + (AP)*4352 + 32); \
  short8 a2_ = *(const short8*)(aB + (AP)*4352 + 64); \
  short8 a3_ = *(const short8*)(aB + (AP)*4352 + 96); \
  ACC = MFMA_(a0_, W[WP][0], ACC, 0, 0, 0); \
  ACC = MFMA_(a1_, W[WP][1], ACC, 0, 0, 0); \
  ACC = MFMA_(a2_, W[WP][2], ACC, 0, 0, 0); \
  ACC = MFMA_(a3_, W[WP][3], ACC, 0, 0, 0); }

#define WSSPM(AP, V) { \
  wB[(AP)*4352]       = f2bf(sspf((V)[0])); \
  wB[(AP)*4352 + 136] = f2bf(sspf((V)[1])); \
  wB[(AP)*4352 + 272] = f2bf(sspf((V)[2])); \
  wB[(AP)*4352 + 408] = f2bf(sspf((V)[3])); }

// Module body; S0 = W-parity of G1's use-buffer (compile-time 0/1).
#define MODBODY(S0) { \
  const float* bp = A.bias_pack + l * 2304; \
  /* G1: gate + W_J -> fm ; load W_I. (no LDS write -> no barrier) */ \
  { float bv_ = bp[col0]; \
    LDW((S0)^1, wtp + 2*16384); \
    gG = Z; \
    { short8 s0_ = *(const short8*)(aS); short8 s1_ = *(const short8*)(aS + 32); \
      gG = MFMA_(s0_, GT0, gG, 0, 0, 0); \
      gG = MFMA_(s1_, GT1, gG, 0, 0, 0); } \
    fm = Z; G128R(0, (S0), fm); \
    for (int r = 0; r < 4; ++r) fm[r] = sspf(fm[r] + bv_); } \
  /* G2: W_I -> proto -> A1 ; load ri1a; prefetch next gate */ \
  { float bv_ = bp[128 + col0]; \
    LDW((S0), wtp + 3*16384); \
    if (l < 4) { \
      GT0 = *(const short8*)(wtp + 16*16384 + goff); \
      GT1 = *(const short8*)(wtp + 16*16384 + goff + 512); \
    } \
    t4 = Z; G128R(0, (S0)^1, t4); \
    for (int r = 0; r < 4; ++r) xf[r] = fm[r] * gG[r] + sspf(t4[r] + bv_); } \
  WSSPM(1, xf); BAR(); \
  /* G3..G8: ri x3 */ \
  { float bv_ = bp[2*128 + col0]; LDW((S0)^1, wtp + 4*16384); \
    t4 = Z; G128R(1, (S0), t4); \
    for (int r = 0; r < 4; ++r) t4[r] += bv_; } \
  WSSPM(0, t4); BAR(); \
  { float bv_ = bp[3*128 + col0]; LDW((S0), wtp + 5*16384); \
    t4 = Z; G128R(0, (S0)^1, t4); \
    for (int r = 0; r < 4; ++r) xf[r] += t4[r] + bv_; } \
  WSSPM(1, xf); BAR(); \
  { float bv_ = bp[4*128 + col0]; LDW((S0)^1, wtp + 6*16384); \
    t4 = Z; G128R(1, (S0), t4); \
    for (int r = 0; r < 4; ++r) t4[r] += bv_; } \
  WSSPM(0, t4); BAR(); \
  { float bv_ = bp[5*128 + col0]; LDW((S0), wtp + 7*16384); \
    t4 = Z; G128R(0, (S0)^1, t4); \
    for (int r = 0; r < 4; ++r) xf[r] += t4[r] + bv_; } \
  WSSPM(1, xf); BAR(); \
  { float bv_ = bp[6*128 + col0]; LDW((S0)^1, wtp + 8*16384); \
    t4 = Z; G128R(1, (S0), t4); \
    for (int r = 0; r < 4; ++r) t4[r] += bv_; } \
  WSSPM(0, t4); BAR(); \
  { float bv_ = bp[7*128 + col0]; LDW((S0), wtp + 9*16384); \
    t4 = Z; G128R(0, (S0)^1, t4); \
    for (int r = 0; r < 4; ++r) xf[r] += t4[r] + bv_; } \
  WSSPM(1, xf); BAR(); \
  /* G9: W_int */ \
  { float bv_ = bp[8*128 + col0]; float gv_ = bp[15*128 + col0]; \
    LDW((S0)^1, wtp + 10*16384); \
    t4 = Z; G128R(1, (S0), t4); \
    for (int r = 0; r < 4; ++r) xf[r] = ff[r] * gv_ + t4[r] + bv_; } \
  WSSPM(0, xf); BAR(); \
  /* G10..G13: ra x2 */ \
  { float bv_ = bp[9*128 + col0]; LDW((S0), wtp + 11*16384); \
    t4 = Z; G128R(0, (S0)^1, t4); \
    for (int r = 0; r < 4; ++r) t4[r] += bv_; } \
  WSSPM(1, t4); BAR(); \
  { float bv_ = bp[10*128 + col0]; LDW((S0)^1, wtp + 12*16384); \
    t4 = Z; G128R(1, (S0), t4); \
    for (int r = 0; r < 4; ++r) xf[r] += t4[r] + bv_; } \
  WSSPM(0, xf); BAR(); \
  { float bv_ = bp[11*128 + col0]; LDW((S0), wtp + 13*16384); \
    t4 = Z; G128R(0, (S0)^1, t4); \
    for (int r = 0; r < 4; ++r) t4[r] += bv_; } \
  WSSPM(1, t4); BAR(); \
  { float bv_ = bp[12*128 + col0]; LDW((S0)^1, wtp + 14*16384); \
    t4 = Z; G128R(1, (S0), t4); \
    for (int r = 0; r < 4; ++r) xf[r] += t4[r] + bv_; } \
  WSSPM(0, xf); BAR(); \
  ff = xf; \
  if (l == 4) { \
    for (int r = 0; r < 4; ++r) \
      A.feat_out[(size_t)(row0 + arow + quad*4 + r) * 128 + col0] = xf[r]; \
  } \
  /* G14: ro1 */ \
  { float bv_ = bp[13*128 + col0]; LDW((S0), wtp + 15*16384); \
    t4 = Z; G128R(0, (S0)^1, t4); \
    for (int r = 0; r < 4; ++r) t4[r] += bv_; } \
  WSSPM(1, t4); BAR(); \
  /* G15: ro2 + energy ; load next module's W_J */ \
  { float bv_ = bp[14*128 + col0]; float wv_ = bp[16*128 + col0]; \
    if (l < 4) LDW((S0)^1, wtp + 17*16384); \
    t4 = Z; G128R(1, (S0), t4); \
    p0 += sspf(xf[0] + t4[0] + bv_) * wv_; \
    p1 += sspf(xf[1] + t4[1] + bv_) * wv_; \
    p2 += sspf(xf[2] + t4[2] + bv_) * wv_; \
    p3 += sspf(xf[3] + t4[3] + bv_) * wv_; } \
  bsum += bp[17*128]; \
  BAR(); }

__global__ __launch_bounds__(1024, 4) void chain_kernel(ChainArgs A) {
  __shared__ __align__(16) unsigned short sA[2][32 * 136]; // 17.4 KB
  __shared__ __align__(16) unsigned short sS[32 * 72];     // 4.5 KB
  __shared__ float sE[32];

  const int tid  = threadIdx.x;
  const int row0 = blockIdx.x * 32;
  const int lane = tid & 63;
  const int w    = tid >> 6;       // 0..15
  const int g    = w >> 3;         // row group 0..1
  const int c    = w & 7;          // col 16-chunk 0..7
  const int l16  = lane & 15;
  const int quad = lane >> 4;
  const int arow = 16 * g;
  const int col0 = 16 * c + l16;

  const int woff = c * 2048 + lane * 8;   // shorts, non-gate slots
  const int goff = c * 1024 + lane * 8;   // shorts, gate slots

  // thread-invariant LDS addresses
  const unsigned short* aB = &sA[0][0] + (arow + l16) * 136 + quad * 8;
  unsigned short*       wB = &sA[0][0] + (arow + quad * 4) * 136 + col0;
  const unsigned short* aS = &sS[0] + (arow + l16) * 72 + quad * 8;

  // prologue: gate(mod0) + W_J(slot1) into registers
  short8 GT0, GT1;
  short8 W[2][4];
  GT0 = *(const short8*)(A.wt + goff);
  GT1 = *(const short8*)(A.wt + goff + 512);
  LDW(0, A.wt + 16384);

  for (int i = tid; i < 32 * 64; i += 1024) {
    int r = i >> 6, k = i & 63;
    sS[r * 72 + k] = f2bf(A.S[(size_t)(row0 + r) * 64 + k]);
  }
  for (int i = tid; i < 32 * 128; i += 1024) {
    int r = i >> 7, k = i & 127;
    sA[0][r * 136 + k] = f2bf(sspf(A.feat_in[(size_t)(row0 + r) * 128 + k]));
  }
  float4v ff;
#pragma unroll
  for (int r = 0; r < 4; ++r)
    ff[r] = A.feat_in[(size_t)(row0 + arow + quad * 4 + r) * 128 + col0];
  if (tid < 32) sE[tid] = 0.0f;
  __syncthreads();

  const float4v Z = {0.f, 0.f, 0.f, 0.f};
  float4v gG, fm, xf, t4;
  float p0 = 0.f, p1 = 0.f, p2 = 0.f, p3 = 0.f, bsum = 0.f;

#pragma unroll 1
  for (int l = 0; l < 5; ++l) {
    const unsigned short* wtp = A.wt + (size_t)l * 16 * 16384;
    if ((l & 1) == 0) MODBODY(0) else MODBODY(1)
  }

  // ---- energy reduction (within 16-lane groups, then across 8 c-waves)
#pragma unroll
  for (int o = 1; o < 16; o <<= 1) {
    p0 += __shfl_xor(p0, o, 64);
    p1 += __shfl_xor(p1, o, 64);
    p2 += __shfl_xor(p2, o, 64);
    p3 += __shfl_xor(p3, o, 64);
  }
  if (l16 == 0) {
    atomicAdd(&sE[arow + quad * 4 + 0], p0);
    atomicAdd(&sE[arow + quad * 4 + 1], p1);
    atomicAdd(&sE[arow + quad * 4 + 2], p2);
    atomicAdd(&sE[arow + quad * 4 + 3], p3);
  }
  BAR();
  if (tid < 32) A.energy[row0 + tid] = sE[tid] + bsum;
}

// ---------------------------------------------------------------------------
extern "C" void kernel_launch(void* const* d_in, const int* in_sizes, int n_in,
                              void* d_out, int out_size, void* d_ws, size_t ws_size,
                              hipStream_t stream) {
  const float* features = (const float*)d_in[1];
  const float* radial   = (const float*)d_in[2];
  const int*   idx12    = (const int*)  d_in[3];
  const float* W_I    = (const float*)d_in[4];
  const float* b_I    = (const float*)d_in[5];
  const float* W_J    = (const float*)d_in[6];
  const float* b_J    = (const float*)d_in[7];
  const float* W_gate = (const float*)d_in[8];
  const float* gvec   = (const float*)d_in[9];
  const float* W_int  = (const float*)d_in[10];
  const float* b_int  = (const float*)d_in[11];
  const float* ri_W1  = (const float*)d_in[12];
  const float* ri_b1  = (const float*)d_in[13];
  const float* ri_W2  = (const float*)d_in[14];
  const float* ri_b2  = (const float*)d_in[15];
  const float* ra_W1  = (const float*)d_in[16];
  const float* ra_b1  = (const float*)d_in[17];
  const float* ra_W2  = (const float*)d_in[18];
  const float* ra_b2  = (const float*)d_in[19];
  const float* ro_W1  = (const float*)d_in[20];
  const float* ro_b1  = (const float*)d_in[21];
  const float* ro_W2  = (const float*)d_in[22];
  const float* ro_b2  = (const float*)d_in[23];
  const float* W_out  = (const float*)d_in[24];
  const float* b_out  = (const float*)d_in[25];

  const int N = in_sizes[1] / 128;   // 8192
  const int P = in_sizes[3] / 2;     // 400000
  const int L = in_sizes[25];        // 5
  const int n2p = 2 * P;
  const int C = (n2p + NB - 1) / NB;

  // ws layout: S | bias_pack | Wt | H | tot | off | pairid
  float* S = (float*)d_ws;
  float* bias_pack = S + (size_t)N * 64;
  unsigned short* Wt = (unsigned short*)(bias_pack + 5 * 2304);
  unsigned int* H      = (unsigned int*)(Wt + (size_t)80 * 16384);
  unsigned int* tot    = H + (size_t)NB * 8192;
  unsigned int* off    = tot + N;
  unsigned int* pairid = off + N + 4;

  // ---- K1: fused weight prep + bias pack + hist
  K1Args k1;
  for (int l = 0; l < L; ++l) {
    const float* fx[16] = {
      W_gate + l * 8192,
      W_J + l * 16384, W_I + l * 16384,
      ri_W1 + (l * 3 + 0) * 16384, ri_W2 + (l * 3 + 0) * 16384,
      ri_W1 + (l * 3 + 1) * 16384, ri_W2 + (l * 3 + 1) * 16384,
      ri_W1 + (l * 3 + 2) * 16384, ri_W2 + (l * 3 + 2) * 16384,
      W_int + l * 16384,
      ra_W1 + (l * 2 + 0) * 16384, ra_W2 + (l * 2 + 0) * 16384,
      ra_W1 + (l * 2 + 1) * 16384, ra_W2 + (l * 2 + 1) * 16384,
      ro_W1 + l * 16384, ro_W2 + l * 16384 };
    for (int t = 0; t < 16; ++t) { k1.wsrc[l * 16 + t] = fx[t]; k1.isgate[l * 16 + t] = (t == 0); }
  }
  const float* bp[17] = { b_J, b_I,
    ri_b1, ri_b2, ri_b1 + 128, ri_b2 + 128, ri_b1 + 256, ri_b2 + 256,
    b_int, ra_b1, ra_b2, ra_b1 + 128, ra_b2 + 128, ro_b1, ro_b2, gvec, W_out };
  int st[17] = {128,128, 384,384,384,384,384,384, 128, 256,256,256,256, 128,128,128,128};
  for (int q = 0; q < 17; ++q) { k1.bp[q] = bp[q]; k1.bstride[q] = st[q]; }
  k1.b_out = b_out;
  k1.idx = idx12; k1.Wt = Wt; k1.bias_pack = bias_pack; k1.H = H;
  k1.n2p = n2p; k1.C = C;
  k1_prep<<<80 + 5 + NB, 256, 0, stream>>>(k1);

  // ---- S via LDS-hist sort + gather (no global atomics)
  col_scan<<<32, 256, 0, stream>>>(H, tot);
  place_pass<<<NB, 256, 0, stream>>>(idx12, H, tot, off, pairid, P, C);
  gather_kernel<<<N, 256, 0, stream>>>(radial, off, pairid, S);

  // ---- fused 5-module chain
  ChainArgs ca;
  ca.feat_in   = features;
  ca.S         = S;
  ca.wt        = Wt;
  ca.bias_pack = bias_pack;
  ca.energy    = (float*)d_out;
  ca.feat_out  = (float*)d_out + N;
  chain_kernel<<<N / 32, 1024, 0, stream>>>(ca);
}

// Round 5
// 324.080 us; speedup vs baseline: 2.3088x; 1.0848x over previous
//
#include <hip/hip_runtime.h>

// ---------------------------------------------------------------------------
// PhysNet stack, MI355X.  v6 = v5 + anti-spill:
//  - R4 counters showed the reg-weight chain SPILLED (VGPR=64 cap, 100MB
//    scratch writes/launch). Fix: amdgpu_waves_per_eu(4,4) pins the register
//    budget at 128 VGPR; module loop FULLY unrolled with compile-time L and
//    parity (no branch-merge live-range joins).
//  - otherwise identical to v5: weights DMA'd to VGPRs (W[2][4] dbuf,
//    prefetch dist 1), raw s_barrier + lgkmcnt(0) only, LDS = A+S tiles.
// ---------------------------------------------------------------------------

#define LN2F 0.69314718055994530942f
#define NB 128   // sort blocks

using short8  = __attribute__((ext_vector_type(8))) short;
using float4v = __attribute__((ext_vector_type(4))) float;

__device__ __forceinline__ float sspf(float x) {
  float ax = fabsf(x);
  return fmaxf(x, 0.0f) + __logf(1.0f + __expf(-ax)) - LN2F;
}

__device__ __forceinline__ unsigned short f2bf(float x) {
  return (unsigned short)((__float_as_uint(x) + 0x8000u) >> 16);  // RTN, <=0.5ulp
}

__device__ __forceinline__ unsigned short f2bf_ne(float x) {  // RTNE for weight prep
  unsigned int u = __float_as_uint(x);
  u += 0x7fffu + ((u >> 16) & 1u);
  return (unsigned short)(u >> 16);
}

// ---------------------------------------------------------------------------
// K1: fused prep_weights (blocks 0..79) + pack_bias (80..84) + hist (85..212)
// Weight pack layout (non-gate slot, 16384 shorts):
//   chunk(c,m,lane): offset c*2048 + m*512 + lane*8; lane=(quad,l16);
//   holds W[k = 8*(4m+quad)+kk][n = 16c+l16], kk=0..7.   (gate: c*1024+m*512)
// ---------------------------------------------------------------------------
struct K1Args {
  const float* wsrc[80];
  int isgate[80];
  const float* bp[17];
  int bstride[17];
  const float* b_out;
  const int* idx;
  unsigned short* Wt;
  float* bias_pack;
  unsigned int* H;
  int n2p, C;
};

__global__ __launch_bounds__(256) void k1_prep(K1Args K) {
  __shared__ unsigned int h[8192];
  int b = blockIdx.x, tid = threadIdx.x;
  if (b < 80) {
    const float* s = K.wsrc[b];
    unsigned short* d = K.Wt + (size_t)b * 16384;
    if (!K.isgate[b]) {
      for (int it = 0; it < 8; ++it) {
        int id = tid + it * 256;
        int lane = id & 63, mm = (id >> 6) & 3, c8 = id >> 8;
        int l16 = lane & 15, quad = lane >> 4;
        int n = 16 * c8 + l16, k0 = 8 * (4 * mm + quad);
        unsigned short tmp[8];
#pragma unroll
        for (int cc = 0; cc < 8; ++cc) tmp[cc] = f2bf_ne(s[(k0 + cc) * 128 + n]);
        *(uint4*)(d + c8 * 2048 + mm * 512 + lane * 8) = *(uint4*)tmp;
      }
    } else {
      for (int it = 0; it < 4; ++it) {
        int id = tid + it * 256;                 // 0..1023
        int lane = id & 63, mm = (id >> 6) & 1, c8 = id >> 7;
        int l16 = lane & 15, quad = lane >> 4;
        int n = 16 * c8 + l16, k0 = 8 * (4 * mm + quad);
        unsigned short tmp[8];
#pragma unroll
        for (int cc = 0; cc < 8; ++cc) tmp[cc] = f2bf_ne(s[(k0 + cc) * 128 + n]);
        *(uint4*)(d + c8 * 1024 + mm * 512 + lane * 8) = *(uint4*)tmp;
      }
    }
  } else if (b < 85) {
    int l = b - 80;
    for (int i = tid; i < 17 * 128; i += 256) {
      int s = i >> 7;
      K.bias_pack[(size_t)l * 2304 + i] = K.bp[s][l * K.bstride[s] + (i & 127)];
    }
    if (tid == 0) K.bias_pack[(size_t)l * 2304 + 17 * 128] = K.b_out[l];
  } else {
    int blk = b - 85;
    for (int i = tid; i < 8192; i += 256) h[i] = 0;
    __syncthreads();
    int s = blk * K.C, e = min(s + K.C, K.n2p);
    for (int i = s + tid; i < e; i += 256) atomicAdd(&h[K.idx[i]], 1u);
    __syncthreads();
    for (int i = tid; i < 8192; i += 256) K.H[(size_t)blk * 8192 + i] = h[i];
  }
}

__global__ __launch_bounds__(256) void col_scan(unsigned int* __restrict__ H,
                                                unsigned int* __restrict__ tot) {
  int a = blockIdx.x * 256 + threadIdx.x;
  unsigned int run = 0;
  for (int b = 0; b < NB; ++b) {
    unsigned int v = H[(size_t)b * 8192 + a];
    H[(size_t)b * 8192 + a] = run;
    run += v;
  }
  tot[a] = run;
}

// place with inline scan of tot (each block redundantly; block 0 publishes off)
__global__ __launch_bounds__(256) void place_pass(const int* __restrict__ idx,
                                                  const unsigned int* __restrict__ H,
                                                  const unsigned int* __restrict__ tot,
                                                  unsigned int* __restrict__ off_out,
                                                  unsigned int* __restrict__ pairid,
                                                  int P, int C) {
  __shared__ unsigned int pos[8192];
  __shared__ unsigned int wt4[4];
  int b = blockIdx.x, tid = threadIdx.x;
  unsigned int local[32], s = 0;
#pragma unroll
  for (int i = 0; i < 32; ++i) { local[i] = tot[tid * 32 + i]; s += local[i]; }
  unsigned int v = s;
  int lane = tid & 63, wv = tid >> 6;
#pragma unroll
  for (int o = 1; o < 64; o <<= 1) {
    unsigned int u = __shfl_up(v, o, 64);
    if (lane >= o) v += u;
  }
  if (lane == 63) wt4[wv] = v;
  __syncthreads();
  unsigned int base = 0;
  for (int k = 0; k < wv; ++k) base += wt4[k];
  unsigned int excl = base + v - s;
#pragma unroll
  for (int i = 0; i < 32; ++i) {
    pos[tid * 32 + i] = excl;
    if (b == 0) off_out[tid * 32 + i] = excl;
    excl += local[i];
  }
  if (b == 0 && tid == 255) off_out[8192] = excl;
  __syncthreads();
  for (int i = tid; i < 8192; i += 256) pos[i] += H[(size_t)b * 8192 + i];
  __syncthreads();
  int n2p = 2 * P;
  int s2 = b * C, e2 = min(s2 + C, n2p);
  for (int i = s2 + tid; i < e2; i += 256) {
    int a = idx[i];
    unsigned int p = atomicAdd(&pos[a], 1u);
    pairid[p] = (i >= P) ? (unsigned int)(i - P) : (unsigned int)i;
  }
}

// Gather: 16-lane group reads a full 256B radial row via dwordx4
__global__ __launch_bounds__(256) void gather_kernel(const float* __restrict__ radial,
                                                     const unsigned int* __restrict__ off,
                                                     const unsigned int* __restrict__ pairid,
                                                     float* __restrict__ S) {
  __shared__ float4v red[3][16];
  int a = blockIdx.x;
  int lane = threadIdx.x & 63, w = threadIdx.x >> 6;
  int grp = lane >> 4, l16v = lane & 15;
  unsigned int b = off[a], e = off[a + 1];
  float4v acc = {0.f, 0.f, 0.f, 0.f};
  for (unsigned int base = b; base < e; base += 128) {
    unsigned int pp[8];
#pragma unroll
    for (int k = 0; k < 8; ++k) {
      unsigned int j = base + k * 16 + w * 4 + grp;
      pp[k] = pairid[j < e ? j : b];          // clamped: always valid
    }
    float4v vv[8];
#pragma unroll
    for (int k = 0; k < 8; ++k)
      vv[k] = *(const float4v*)(radial + (size_t)pp[k] * 64 + l16v * 4);
#pragma unroll
    for (int k = 0; k < 8; ++k) {
      unsigned int j = base + k * 16 + w * 4 + grp;
      if (j < e) acc += vv[k];
    }
  }
#pragma unroll
  for (int o = 16; o < 64; o <<= 1) {
#pragma unroll
    for (int cc = 0; cc < 4; ++cc) acc[cc] += __shfl_xor(acc[cc], o, 64);
  }
  if (w > 0 && grp == 0) red[w - 1][l16v] = acc;
  __syncthreads();
  if (w == 0 && grp == 0) {
    acc += red[0][l16v];
    acc += red[1][l16v];
    acc += red[2][l16v];
    *(float4v*)(S + (size_t)a * 64 + l16v * 4) = acc;
  }
}

// ---------------------------------------------------------------------------
// Chain v6: 256 blocks x 1024 threads (16 waves), 1 block/CU, 4 waves/EU
// pinned. Weights in registers; module loop fully unrolled (compile-time L).
// ---------------------------------------------------------------------------
struct ChainArgs {
  const float* feat_in;
  const float* S;
  const unsigned short* wt;      // 80 slots x 16384 shorts (fragment order)
  const float* bias_pack;        // 5 x 2304 floats
  float* feat_out;
  float* energy;
};

#define MFMA_ __builtin_amdgcn_mfma_f32_16x16x32_bf16

#define BAR() { __builtin_amdgcn_sched_barrier(0); \
  asm volatile("s_waitcnt lgkmcnt(0)" ::: "memory"); \
  __builtin_amdgcn_s_barrier(); \
  __builtin_amdgcn_sched_barrier(0); }

#define LDW(WP, sp) { \
  const unsigned short* wp_ = (sp) + woff; \
  W[WP][0] = *(const short8*)(wp_); \
  W[WP][1] = *(const short8*)(wp_ + 512); \
  W[WP][2] = *(const short8*)(wp_ + 1024); \
  W[WP][3] = *(const short8*)(wp_ + 1536); }

#define G128R(AP, WP, ACC) { \
  short8 a0_ = *(const short8*)(aB + (AP)*4352); \
  short8 a1_ = *(const short8*)(aB + (AP)*4352 + 32); \
  short8 a2_ = *(const short8*)(aB + (AP)*4352 + 64); \
  short8 a3_ = *(const short8*)(aB + (AP)*4352 + 96); \
  ACC = MFMA_(a0_, W[WP][0], ACC, 0, 0, 0); \
  ACC = MFMA_(a1_, W[WP][1], ACC, 0, 0, 0); \
  ACC = MFMA_(a2_, W[WP][2], ACC, 0, 0, 0); \
  ACC = MFMA_(a3_, W[WP][3], ACC, 0, 0, 0); }

#define WSSPM(AP, V) { \
  wB[(AP)*4352]       = f2bf(sspf((V)[0])); \
  wB[(AP)*4352 + 136] = f2bf(sspf((V)[1])); \
  wB[(AP)*4352 + 272] = f2bf(sspf((V)[2])); \
  wB[(AP)*4352 + 408] = f2bf(sspf((V)[3])); }

// Module body; L = module index (0..4), S0 = W-parity of G1's use-buffer.
// Both are LITERALS -> every index below is compile-time.
#define MODBODY(L, S0) { \
  const float* bp = A.bias_pack + (L) * 2304; \
  const unsigned short* wtp = A.wt + (size_t)(L) * 16 * 16384; \
  /* G1: gate + W_J -> fm ; load W_I. (no LDS write -> no barrier) */ \
  { float bv_ = bp[col0]; \
    LDW((S0)^1, wtp + 2*16384); \
    gG = Z; \
    { short8 s0_ = *(const short8*)(aS); short8 s1_ = *(const short8*)(aS + 32); \
      gG = MFMA_(s0_, GT0, gG, 0, 0, 0); \
      gG = MFMA_(s1_, GT1, gG, 0, 0, 0); } \
    fm = Z; G128R(0, (S0), fm); \
    for (int r = 0; r < 4; ++r) fm[r] = sspf(fm[r] + bv_); } \
  /* G2: W_I -> proto -> A1 ; load ri1a; prefetch next gate */ \
  { float bv_ = bp[128 + col0]; \
    LDW((S0), wtp + 3*16384); \
    if ((L) < 4) { \
      GT0 = *(const short8*)(wtp + 16*16384 + goff); \
      GT1 = *(const short8*)(wtp + 16*16384 + goff + 512); \
    } \
    t4 = Z; G128R(0, (S0)^1, t4); \
    for (int r = 0; r < 4; ++r) xf[r] = fm[r] * gG[r] + sspf(t4[r] + bv_); } \
  WSSPM(1, xf); BAR(); \
  /* G3..G8: ri x3 */ \
  { float bv_ = bp[2*128 + col0]; LDW((S0)^1, wtp + 4*16384); \
    t4 = Z; G128R(1, (S0), t4); \
    for (int r = 0; r < 4; ++r) t4[r] += bv_; } \
  WSSPM(0, t4); BAR(); \
  { float bv_ = bp[3*128 + col0]; LDW((S0), wtp + 5*16384); \
    t4 = Z; G128R(0, (S0)^1, t4); \
    for (int r = 0; r < 4; ++r) xf[r] += t4[r] + bv_; } \
  WSSPM(1, xf); BAR(); \
  { float bv_ = bp[4*128 + col0]; LDW((S0)^1, wtp + 6*16384); \
    t4 = Z; G128R(1, (S0), t4); \
    for (int r = 0; r < 4; ++r) t4[r] += bv_; } \
  WSSPM(0, t4); BAR(); \
  { float bv_ = bp[5*128 + col0]; LDW((S0), wtp + 7*16384); \
    t4 = Z; G128R(0, (S0)^1, t4); \
    for (int r = 0; r < 4; ++r) xf[r] += t4[r] + bv_; } \
  WSSPM(1, xf); BAR(); \
  { float bv_ = bp[6*128 + col0]; LDW((S0)^1, wtp + 8*16384); \
    t4 = Z; G128R(1, (S0), t4); \
    for (int r = 0; r < 4; ++r) t4[r] += bv_; } \
  WSSPM(0, t4); BAR(); \
  { float bv_ = bp[7*128 + col0]; LDW((S0), wtp + 9*16384); \
    t4 = Z; G128R(0, (S0)^1, t4); \
    for (int r = 0; r < 4; ++r) xf[r] += t4[r] + bv_; } \
  WSSPM(1, xf); BAR(); \
  /* G9: W_int */ \
  { float bv_ = bp[8*128 + col0]; float gv_ = bp[15*128 + col0]; \
    LDW((S0)^1, wtp + 10*16384); \
    t4 = Z; G128R(1, (S0), t4); \
    for (int r = 0; r < 4; ++r) xf[r] = ff[r] * gv_ + t4[r] + bv_; } \
  WSSPM(0, xf); BAR(); \
  /* G10..G13: ra x2 */ \
  { float bv_ = bp[9*128 + col0]; LDW((S0), wtp + 11*16384); \
    t4 = Z; G128R(0, (S0)^1, t4); \
    for (int r = 0; r < 4; ++r) t4[r] += bv_; } \
  WSSPM(1, t4); BAR(); \
  { float bv_ = bp[10*128 + col0]; LDW((S0)^1, wtp + 12*16384); \
    t4 = Z; G128R(1, (S0), t4); \
    for (int r = 0; r < 4; ++r) xf[r] += t4[r] + bv_; } \
  WSSPM(0, xf); BAR(); \
  { float bv_ = bp[11*128 + col0]; LDW((S0), wtp + 13*16384); \
    t4 = Z; G128R(0, (S0)^1, t4); \
    for (int r = 0; r < 4; ++r) t4[r] += bv_; } \
  WSSPM(1, t4); BAR(); \
  { float bv_ = bp[12*128 + col0]; LDW((S0)^1, wtp + 14*16384); \
    t4 = Z; G128R(1, (S0), t4); \
    for (int r = 0; r < 4; ++r) xf[r] += t4[r] + bv_; } \
  WSSPM(0, xf); BAR(); \
  ff = xf; \
  if ((L) == 4) { \
    for (int r = 0; r < 4; ++r) \
      A.feat_out[(size_t)(row0 + arow + quad*4 + r) * 128 + col0] = xf[r]; \
  } \
  /* G14: ro1 */ \
  { float bv_ = bp[13*128 + col0]; LDW((S0), wtp + 15*16384); \
    t4 = Z; G128R(0, (S0)^1, t4); \
    for (int r = 0; r < 4; ++r) t4[r] += bv_; } \
  WSSPM(1, t4); BAR(); \
  /* G15: ro2 + energy ; load next module's W_J */ \
  { float bv_ = bp[14*128 + col0]; float wv_ = bp[16*128 + col0]; \
    if ((L) < 4) LDW((S0)^1, wtp + 17*16384); \
    t4 = Z; G128R(1, (S0), t4); \
    p0 += sspf(xf[0] + t4[0] + bv_) * wv_; \
    p1 += sspf(xf[1] + t4[1] + bv_) * wv_; \
    p2 += sspf(xf[2] + t4[2] + bv_) * wv_; \
    p3 += sspf(xf[3] + t4[3] + bv_) * wv_; } \
  bsum += bp[17*128]; \
  BAR(); }

__global__ __launch_bounds__(1024, 4)
__attribute__((amdgpu_waves_per_eu(4, 4)))
void chain_kernel(ChainArgs A) {
  __shared__ __align__(16) unsigned short sA[2][32 * 136]; // 17.4 KB
  __shared__ __align__(16) unsigned short sS[32 * 72];     // 4.5 KB
  __shared__ float sE[32];

  const int tid  = threadIdx.x;
  const int row0 = blockIdx.x * 32;
  const int lane = tid & 63;
  const int w    = tid >> 6;       // 0..15
  const int g    = w >> 3;         // row group 0..1
  const int c    = w & 7;          // col 16-chunk 0..7
  const int l16  = lane & 15;
  const int quad = lane >> 4;
  const int arow = 16 * g;
  const int col0 = 16 * c + l16;

  const int woff = c * 2048 + lane * 8;   // shorts, non-gate slots
  const int goff = c * 1024 + lane * 8;   // shorts, gate slots

  // thread-invariant LDS addresses
  const unsigned short* aB = &sA[0][0] + (arow + l16) * 136 + quad * 8;
  unsigned short*       wB = &sA[0][0] + (arow + quad * 4) * 136 + col0;
  const unsigned short* aS = &sS[0] + (arow + l16) * 72 + quad * 8;

  // prologue: gate(mod0) + W_J(slot1) into registers
  short8 GT0, GT1;
  short8 W[2][4];
  GT0 = *(const short8*)(A.wt + goff);
  GT1 = *(const short8*)(A.wt + goff + 512);
  LDW(0, A.wt + 16384);

  for (int i = tid; i < 32 * 64; i += 1024) {
    int r = i >> 6, k = i & 63;
    sS[r * 72 + k] = f2bf(A.S[(size_t)(row0 + r) * 64 + k]);
  }
  for (int i = tid; i < 32 * 128; i += 1024) {
    int r = i >> 7, k = i & 127;
    sA[0][r * 136 + k] = f2bf(sspf(A.feat_in[(size_t)(row0 + r) * 128 + k]));
  }
  float4v ff;
#pragma unroll
  for (int r = 0; r < 4; ++r)
    ff[r] = A.feat_in[(size_t)(row0 + arow + quad * 4 + r) * 128 + col0];
  if (tid < 32) sE[tid] = 0.0f;
  __syncthreads();

  const float4v Z = {0.f, 0.f, 0.f, 0.f};
  float4v gG, fm, xf, t4;
  float p0 = 0.f, p1 = 0.f, p2 = 0.f, p3 = 0.f, bsum = 0.f;

  // fully unrolled module chain: parity alternates 0,1,0,1,0
  MODBODY(0, 0)
  MODBODY(1, 1)
  MODBODY(2, 0)
  MODBODY(3, 1)
  MODBODY(4, 0)

  // ---- energy reduction (within 16-lane groups, then across 8 c-waves)
#pragma unroll
  for (int o = 1; o < 16; o <<= 1) {
    p0 += __shfl_xor(p0, o, 64);
    p1 += __shfl_xor(p1, o, 64);
    p2 += __shfl_xor(p2, o, 64);
    p3 += __shfl_xor(p3, o, 64);
  }
  if (l16 == 0) {
    atomicAdd(&sE[arow + quad * 4 + 0], p0);
    atomicAdd(&sE[arow + quad * 4 + 1], p1);
    atomicAdd(&sE[arow + quad * 4 + 2], p2);
    atomicAdd(&sE[arow + quad * 4 + 3], p3);
  }
  BAR();
  if (tid < 32) A.energy[row0 + tid] = sE[tid] + bsum;
}

// ---------------------------------------------------------------------------
extern "C" void kernel_launch(void* const* d_in, const int* in_sizes, int n_in,
                              void* d_out, int out_size, void* d_ws, size_t ws_size,
                              hipStream_t stream) {
  const float* features = (const float*)d_in[1];
  const float* radial   = (const float*)d_in[2];
  const int*   idx12    = (const int*)  d_in[3];
  const float* W_I    = (const float*)d_in[4];
  const float* b_I    = (const float*)d_in[5];
  const float* W_J    = (const float*)d_in[6];
  const float* b_J    = (const float*)d_in[7];
  const float* W_gate = (const float*)d_in[8];
  const float* gvec   = (const float*)d_in[9];
  const float* W_int  = (const float*)d_in[10];
  const float* b_int  = (const float*)d_in[11];
  const float* ri_W1  = (const float*)d_in[12];
  const float* ri_b1  = (const float*)d_in[13];
  const float* ri_W2  = (const float*)d_in[14];
  const float* ri_b2  = (const float*)d_in[15];
  const float* ra_W1  = (const float*)d_in[16];
  const float* ra_b1  = (const float*)d_in[17];
  const float* ra_W2  = (const float*)d_in[18];
  const float* ra_b2  = (const float*)d_in[19];
  const float* ro_W1  = (const float*)d_in[20];
  const float* ro_b1  = (const float*)d_in[21];
  const float* ro_W2  = (const float*)d_in[22];
  const float* ro_b2  = (const float*)d_in[23];
  const float* W_out  = (const float*)d_in[24];
  const float* b_out  = (const float*)d_in[25];

  const int N = in_sizes[1] / 128;   // 8192
  const int P = in_sizes[3] / 2;     // 400000
  const int L = in_sizes[25];        // 5
  const int n2p = 2 * P;
  const int C = (n2p + NB - 1) / NB;

  // ws layout: S | bias_pack | Wt | H | tot | off | pairid
  float* S = (float*)d_ws;
  float* bias_pack = S + (size_t)N * 64;
  unsigned short* Wt = (unsigned short*)(bias_pack + 5 * 2304);
  unsigned int* H      = (unsigned int*)(Wt + (size_t)80 * 16384);
  unsigned int* tot    = H + (size_t)NB * 8192;
  unsigned int* off    = tot + N;
  unsigned int* pairid = off + N + 4;

  // ---- K1: fused weight prep + bias pack + hist
  K1Args k1;
  for (int l = 0; l < L; ++l) {
    const float* fx[16] = {
      W_gate + l * 8192,
      W_J + l * 16384, W_I + l * 16384,
      ri_W1 + (l * 3 + 0) * 16384, ri_W2 + (l * 3 + 0) * 16384,
      ri_W1 + (l * 3 + 1) * 16384, ri_W2 + (l * 3 + 1) * 16384,
      ri_W1 + (l * 3 + 2) * 16384, ri_W2 + (l * 3 + 2) * 16384,
      W_int + l * 16384,
      ra_W1 + (l * 2 + 0) * 16384, ra_W2 + (l * 2 + 0) * 16384,
      ra_W1 + (l * 2 + 1) * 16384, ra_W2 + (l * 2 + 1) * 16384,
      ro_W1 + l * 16384, ro_W2 + l * 16384 };
    for (int t = 0; t < 16; ++t) { k1.wsrc[l * 16 + t] = fx[t]; k1.isgate[l * 16 + t] = (t == 0); }
  }
  const float* bp[17] = { b_J, b_I,
    ri_b1, ri_b2, ri_b1 + 128, ri_b2 + 128, ri_b1 + 256, ri_b2 + 256,
    b_int, ra_b1, ra_b2, ra_b1 + 128, ra_b2 + 128, ro_b1, ro_b2, gvec, W_out };
  int st[17] = {128,128, 384,384,384,384,384,384, 128, 256,256,256,256, 128,128,128,128};
  for (int q = 0; q < 17; ++q) { k1.bp[q] = bp[q]; k1.bstride[q] = st[q]; }
  k1.b_out = b_out;
  k1.idx = idx12; k1.Wt = Wt; k1.bias_pack = bias_pack; k1.H = H;
  k1.n2p = n2p; k1.C = C;
  k1_prep<<<80 + 5 + NB, 256, 0, stream>>>(k1);

  // ---- S via LDS-hist sort + gather (no global atomics)
  col_scan<<<32, 256, 0, stream>>>(H, tot);
  place_pass<<<NB, 256, 0, stream>>>(idx12, H, tot, off, pairid, P, C);
  gather_kernel<<<N, 256, 0, stream>>>(radial, off, pairid, S);

  // ---- fused 5-module chain
  ChainArgs ca;
  ca.feat_in   = features;
  ca.S         = S;
  ca.wt        = Wt;
  ca.bias_pack = bias_pack;
  ca.energy    = (float*)d_out;
  ca.feat_out  = (float*)d_out + N;
  chain_kernel<<<N / 32, 1024, 0, stream>>>(ca);
}

// Round 6
// 320.773 us; speedup vs baseline: 2.3326x; 1.0103x over previous
//
#include <hip/hip_runtime.h>

// ---------------------------------------------------------------------------
// PhysNet stack, MI355X.  v7 = v6 + split barrier domains + bias-as-acc-init:
//  - chain: 16-row / 8-wave / 512 blocks (2 blocks/CU). Row-groups are fully
//    independent; with reg-resident weights the split adds NO extra L2
//    traffic (unlike v2). Two unsynchronized barrier domains per CU overlap
//    one block's VALU burst with the other's MFMA/barrier wait.
//  - MFMA accumulators initialized with the BIAS (C-in is free) -> the
//    post-MFMA "+bv" pass is gone. Per-module bias preload into registers
//    (17 VGPR, static indices, burst at module start).
//  - weights in VGPRs (W[2][4] dbuf, prefetch dist 1), raw s_barrier +
//    lgkmcnt(0), fully unrolled modules. S-path unchanged.
// ---------------------------------------------------------------------------

#define LN2F 0.69314718055994530942f
#define NB 128   // sort blocks

using short8  = __attribute__((ext_vector_type(8))) short;
using float4v = __attribute__((ext_vector_type(4))) float;

__device__ __forceinline__ float sspf(float x) {
  float ax = fabsf(x);
  return fmaxf(x, 0.0f) + __logf(1.0f + __expf(-ax)) - LN2F;
}

__device__ __forceinline__ unsigned short f2bf(float x) {
  return (unsigned short)((__float_as_uint(x) + 0x8000u) >> 16);  // RTN, <=0.5ulp
}

__device__ __forceinline__ unsigned short f2bf_ne(float x) {  // RTNE for weight prep
  unsigned int u = __float_as_uint(x);
  u += 0x7fffu + ((u >> 16) & 1u);
  return (unsigned short)(u >> 16);
}

// ---------------------------------------------------------------------------
// K1: fused prep_weights (blocks 0..79) + pack_bias (80..84) + hist (85..212)
// Weight pack layout (non-gate slot, 16384 shorts):
//   chunk(c,m,lane): offset c*2048 + m*512 + lane*8; lane=(quad,l16);
//   holds W[k = 8*(4m+quad)+kk][n = 16c+l16], kk=0..7.   (gate: c*1024+m*512)
// ---------------------------------------------------------------------------
struct K1Args {
  const float* wsrc[80];
  int isgate[80];
  const float* bp[17];
  int bstride[17];
  const float* b_out;
  const int* idx;
  unsigned short* Wt;
  float* bias_pack;
  unsigned int* H;
  int n2p, C;
};

__global__ __launch_bounds__(256) void k1_prep(K1Args K) {
  __shared__ unsigned int h[8192];
  int b = blockIdx.x, tid = threadIdx.x;
  if (b < 80) {
    const float* s = K.wsrc[b];
    unsigned short* d = K.Wt + (size_t)b * 16384;
    if (!K.isgate[b]) {
      for (int it = 0; it < 8; ++it) {
        int id = tid + it * 256;
        int lane = id & 63, mm = (id >> 6) & 3, c8 = id >> 8;
        int l16 = lane & 15, quad = lane >> 4;
        int n = 16 * c8 + l16, k0 = 8 * (4 * mm + quad);
        unsigned short tmp[8];
#pragma unroll
        for (int cc = 0; cc < 8; ++cc) tmp[cc] = f2bf_ne(s[(k0 + cc) * 128 + n]);
        *(uint4*)(d + c8 * 2048 + mm * 512 + lane * 8) = *(uint4*)tmp;
      }
    } else {
      for (int it = 0; it < 4; ++it) {
        int id = tid + it * 256;                 // 0..1023
        int lane = id & 63, mm = (id >> 6) & 1, c8 = id >> 7;
        int l16 = lane & 15, quad = lane >> 4;
        int n = 16 * c8 + l16, k0 = 8 * (4 * mm + quad);
        unsigned short tmp[8];
#pragma unroll
        for (int cc = 0; cc < 8; ++cc) tmp[cc] = f2bf_ne(s[(k0 + cc) * 128 + n]);
        *(uint4*)(d + c8 * 1024 + mm * 512 + lane * 8) = *(uint4*)tmp;
      }
    }
  } else if (b < 85) {
    int l = b - 80;
    for (int i = tid; i < 17 * 128; i += 256) {
      int s = i >> 7;
      K.bias_pack[(size_t)l * 2304 + i] = K.bp[s][l * K.bstride[s] + (i & 127)];
    }
    if (tid == 0) K.bias_pack[(size_t)l * 2304 + 17 * 128] = K.b_out[l];
  } else {
    int blk = b - 85;
    for (int i = tid; i < 8192; i += 256) h[i] = 0;
    __syncthreads();
    int s = blk * K.C, e = min(s + K.C, K.n2p);
    for (int i = s + tid; i < e; i += 256) atomicAdd(&h[K.idx[i]], 1u);
    __syncthreads();
    for (int i = tid; i < 8192; i += 256) K.H[(size_t)blk * 8192 + i] = h[i];
  }
}

__global__ __launch_bounds__(256) void col_scan(unsigned int* __restrict__ H,
                                                unsigned int* __restrict__ tot) {
  int a = blockIdx.x * 256 + threadIdx.x;
  unsigned int run = 0;
  for (int b = 0; b < NB; ++b) {
    unsigned int v = H[(size_t)b * 8192 + a];
    H[(size_t)b * 8192 + a] = run;
    run += v;
  }
  tot[a] = run;
}

// place with inline scan of tot (each block redundantly; block 0 publishes off)
__global__ __launch_bounds__(256) void place_pass(const int* __restrict__ idx,
                                                  const unsigned int* __restrict__ H,
                                                  const unsigned int* __restrict__ tot,
                                                  unsigned int* __restrict__ off_out,
                                                  unsigned int* __restrict__ pairid,
                                                  int P, int C) {
  __shared__ unsigned int pos[8192];
  __shared__ unsigned int wt4[4];
  int b = blockIdx.x, tid = threadIdx.x;
  unsigned int local[32], s = 0;
#pragma unroll
  for (int i = 0; i < 32; ++i) { local[i] = tot[tid * 32 + i]; s += local[i]; }
  unsigned int v = s;
  int lane = tid & 63, wv = tid >> 6;
#pragma unroll
  for (int o = 1; o < 64; o <<= 1) {
    unsigned int u = __shfl_up(v, o, 64);
    if (lane >= o) v += u;
  }
  if (lane == 63) wt4[wv] = v;
  __syncthreads();
  unsigned int base = 0;
  for (int k = 0; k < wv; ++k) base += wt4[k];
  unsigned int excl = base + v - s;
#pragma unroll
  for (int i = 0; i < 32; ++i) {
    pos[tid * 32 + i] = excl;
    if (b == 0) off_out[tid * 32 + i] = excl;
    excl += local[i];
  }
  if (b == 0 && tid == 255) off_out[8192] = excl;
  __syncthreads();
  for (int i = tid; i < 8192; i += 256) pos[i] += H[(size_t)b * 8192 + i];
  __syncthreads();
  int n2p = 2 * P;
  int s2 = b * C, e2 = min(s2 + C, n2p);
  for (int i = s2 + tid; i < e2; i += 256) {
    int a = idx[i];
    unsigned int p = atomicAdd(&pos[a], 1u);
    pairid[p] = (i >= P) ? (unsigned int)(i - P) : (unsigned int)i;
  }
}

// Gather: 16-lane group reads a full 256B radial row via dwordx4
__global__ __launch_bounds__(256) void gather_kernel(const float* __restrict__ radial,
                                                     const unsigned int* __restrict__ off,
                                                     const unsigned int* __restrict__ pairid,
                                                     float* __restrict__ S) {
  __shared__ float4v red[3][16];
  int a = blockIdx.x;
  int lane = threadIdx.x & 63, w = threadIdx.x >> 6;
  int grp = lane >> 4, l16v = lane & 15;
  unsigned int b = off[a], e = off[a + 1];
  float4v acc = {0.f, 0.f, 0.f, 0.f};
  for (unsigned int base = b; base < e; base += 128) {
    unsigned int pp[8];
#pragma unroll
    for (int k = 0; k < 8; ++k) {
      unsigned int j = base + k * 16 + w * 4 + grp;
      pp[k] = pairid[j < e ? j : b];          // clamped: always valid
    }
    float4v vv[8];
#pragma unroll
    for (int k = 0; k < 8; ++k)
      vv[k] = *(const float4v*)(radial + (size_t)pp[k] * 64 + l16v * 4);
#pragma unroll
    for (int k = 0; k < 8; ++k) {
      unsigned int j = base + k * 16 + w * 4 + grp;
      if (j < e) acc += vv[k];
    }
  }
#pragma unroll
  for (int o = 16; o < 64; o <<= 1) {
#pragma unroll
    for (int cc = 0; cc < 4; ++cc) acc[cc] += __shfl_xor(acc[cc], o, 64);
  }
  if (w > 0 && grp == 0) red[w - 1][l16v] = acc;
  __syncthreads();
  if (w == 0 && grp == 0) {
    acc += red[0][l16v];
    acc += red[1][l16v];
    acc += red[2][l16v];
    *(float4v*)(S + (size_t)a * 64 + l16v * 4) = acc;
  }
}

// ---------------------------------------------------------------------------
// Chain v7: 512 blocks x 512 threads (8 waves), 2 blocks/CU, 4 waves/EU.
// Weights in registers; modules fully unrolled; acc init = bias.
// ---------------------------------------------------------------------------
struct ChainArgs {
  const float* feat_in;
  const float* S;
  const unsigned short* wt;      // 80 slots x 16384 shorts (fragment order)
  const float* bias_pack;        // 5 x 2304 floats
  float* feat_out;
  float* energy;
};

#define MFMA_ __builtin_amdgcn_mfma_f32_16x16x32_bf16
#define APOFF 2176   // shorts between sA[0] and sA[1] (16*136)

#define BAR() { __builtin_amdgcn_sched_barrier(0); \
  asm volatile("s_waitcnt lgkmcnt(0)" ::: "memory"); \
  __builtin_amdgcn_s_barrier(); \
  __builtin_amdgcn_sched_barrier(0); }

#define LDW(WP, sp) { \
  const unsigned short* wp_ = (sp) + woff; \
  W[WP][0] = *(const short8*)(wp_); \
  W[WP][1] = *(const short8*)(wp_ + 512); \
  W[WP][2] = *(const short8*)(wp_ + 1024); \
  W[WP][3] = *(const short8*)(wp_ + 1536); }

#define BINI(ACC, B) { (ACC)[0] = (B); (ACC)[1] = (B); (ACC)[2] = (B); (ACC)[3] = (B); }

#define G128R(AP, WP, ACC) { \
  short8 a0_ = *(const short8*)(aB + (AP)*APOFF); \
  short8 a1_ = *(const short8*)(aB + (AP)*APOFF + 32); \
  short8 a2_ = *(const short8*)(aB + (AP)*APOFF + 64); \
  short8 a3_ = *(const short8*)(aB + (AP)*APOFF + 96); \
  ACC = MFMA_(a0_, W[WP][0], ACC, 0, 0, 0); \
  ACC = MFMA_(a1_, W[WP][1], ACC, 0, 0, 0); \
  ACC = MFMA_(a2_, W[WP][2], ACC, 0, 0, 0); \
  ACC = MFMA_(a3_, W[WP][3], ACC, 0, 0, 0); }

#define WSSPM(AP, V) { \
  wB[(AP)*APOFF]       = f2bf(sspf((V)[0])); \
  wB[(AP)*APOFF + 136] = f2bf(sspf((V)[1])); \
  wB[(AP)*APOFF + 272] = f2bf(sspf((V)[2])); \
  wB[(AP)*APOFF + 408] = f2bf(sspf((V)[3])); }

// Module body; L = module index (0..4), S0 = W-parity of G1's use-buffer.
// Both LITERALS -> all indices compile-time. Biases preloaded into bW[].
#define MODBODY(L, S0) { \
  const float* bp = A.bias_pack + (L) * 2304; \
  const unsigned short* wtp = A.wt + (size_t)(L) * 16 * 16384; \
  float bW[15]; \
  _Pragma("unroll") \
  for (int q = 0; q < 15; ++q) bW[q] = bp[q * 128 + col0]; \
  float gvv = bp[15 * 128 + col0], wvv = bp[16 * 128 + col0]; \
  /* G1: gate + W_J -> fm ; load W_I. (no LDS write -> no barrier) */ \
  { LDW((S0)^1, wtp + 2*16384); \
    gG = Z; \
    { short8 s0_ = *(const short8*)(aS); short8 s1_ = *(const short8*)(aS + 32); \
      gG = MFMA_(s0_, GT0, gG, 0, 0, 0); \
      gG = MFMA_(s1_, GT1, gG, 0, 0, 0); } \
    BINI(fm, bW[0]); G128R(0, (S0), fm); \
    for (int r = 0; r < 4; ++r) fm[r] = sspf(fm[r]); } \
  /* G2: W_I -> proto -> A1 ; load ri1a; prefetch next gate */ \
  { LDW((S0), wtp + 3*16384); \
    if ((L) < 4) { \
      GT0 = *(const short8*)(wtp + 16*16384 + goff); \
      GT1 = *(const short8*)(wtp + 16*16384 + goff + 512); \
    } \
    BINI(t4, bW[1]); G128R(0, (S0)^1, t4); \
    for (int r = 0; r < 4; ++r) xf[r] = fm[r] * gG[r] + sspf(t4[r]); } \
  WSSPM(1, xf); BAR(); \
  /* G3..G8: ri x3 */ \
  { LDW((S0)^1, wtp + 4*16384); BINI(t4, bW[2]); G128R(1, (S0), t4); } \
  WSSPM(0, t4); BAR(); \
  { LDW((S0), wtp + 5*16384); BINI(t4, bW[3]); G128R(0, (S0)^1, t4); \
    for (int r = 0; r < 4; ++r) xf[r] += t4[r]; } \
  WSSPM(1, xf); BAR(); \
  { LDW((S0)^1, wtp + 6*16384); BINI(t4, bW[4]); G128R(1, (S0), t4); } \
  WSSPM(0, t4); BAR(); \
  { LDW((S0), wtp + 7*16384); BINI(t4, bW[5]); G128R(0, (S0)^1, t4); \
    for (int r = 0; r < 4; ++r) xf[r] += t4[r]; } \
  WSSPM(1, xf); BAR(); \
  { LDW((S0)^1, wtp + 8*16384); BINI(t4, bW[6]); G128R(1, (S0), t4); } \
  WSSPM(0, t4); BAR(); \
  { LDW((S0), wtp + 9*16384); BINI(t4, bW[7]); G128R(0, (S0)^1, t4); \
    for (int r = 0; r < 4; ++r) xf[r] += t4[r]; } \
  WSSPM(1, xf); BAR(); \
  /* G9: W_int */ \
  { LDW((S0)^1, wtp + 10*16384); BINI(t4, bW[8]); G128R(1, (S0), t4); \
    for (int r = 0; r < 4; ++r) xf[r] = ff[r] * gvv + t4[r]; } \
  WSSPM(0, xf); BAR(); \
  /* G10..G13: ra x2 */ \
  { LDW((S0), wtp + 11*16384); BINI(t4, bW[9]); G128R(0, (S0)^1, t4); } \
  WSSPM(1, t4); BAR(); \
  { LDW((S0)^1, wtp + 12*16384); BINI(t4, bW[10]); G128R(1, (S0), t4); \
    for (int r = 0; r < 4; ++r) xf[r] += t4[r]; } \
  WSSPM(0, xf); BAR(); \
  { LDW((S0), wtp + 13*16384); BINI(t4, bW[11]); G128R(0, (S0)^1, t4); } \
  WSSPM(1, t4); BAR(); \
  { LDW((S0)^1, wtp + 14*16384); BINI(t4, bW[12]); G128R(1, (S0), t4); \
    for (int r = 0; r < 4; ++r) xf[r] += t4[r]; } \
  WSSPM(0, xf); BAR(); \
  ff = xf; \
  if ((L) == 4) { \
    for (int r = 0; r < 4; ++r) \
      A.feat_out[(size_t)(row0 + quad*4 + r) * 128 + col0] = xf[r]; \
  } \
  /* G14: ro1 */ \
  { LDW((S0), wtp + 15*16384); BINI(t4, bW[13]); G128R(0, (S0)^1, t4); } \
  WSSPM(1, t4); BAR(); \
  /* G15: ro2 + energy ; load next module's W_J */ \
  { if ((L) < 4) LDW((S0)^1, wtp + 17*16384); \
    BINI(t4, bW[14]); G128R(1, (S0), t4); \
    p0 += sspf(xf[0] + t4[0]) * wvv; \
    p1 += sspf(xf[1] + t4[1]) * wvv; \
    p2 += sspf(xf[2] + t4[2]) * wvv; \
    p3 += sspf(xf[3] + t4[3]) * wvv; } \
  bsum += bp[17*128]; \
  BAR(); }

__global__ __launch_bounds__(512)
__attribute__((amdgpu_waves_per_eu(4, 4)))
void chain_kernel(ChainArgs A) {
  __shared__ __align__(16) unsigned short sA[2][16 * 136]; // 8.7 KB
  __shared__ __align__(16) unsigned short sS[16 * 72];     // 2.25 KB
  __shared__ float sE[16];

  const int tid  = threadIdx.x;
  const int row0 = blockIdx.x * 16;
  const int lane = tid & 63;
  const int c    = tid >> 6;       // 0..7 = col 16-chunk
  const int l16  = lane & 15;
  const int quad = lane >> 4;
  const int col0 = 16 * c + l16;

  const int woff = c * 2048 + lane * 8;   // shorts, non-gate slots
  const int goff = c * 1024 + lane * 8;   // shorts, gate slots

  // thread-invariant LDS addresses
  const unsigned short* aB = &sA[0][0] + l16 * 136 + quad * 8;
  unsigned short*       wB = &sA[0][0] + (quad * 4) * 136 + col0;
  const unsigned short* aS = &sS[0] + l16 * 72 + quad * 8;

  // prologue: gate(mod0) + W_J(slot1) into registers
  short8 GT0, GT1;
  short8 W[2][4];
  GT0 = *(const short8*)(A.wt + goff);
  GT1 = *(const short8*)(A.wt + goff + 512);
  LDW(0, A.wt + 16384);

  for (int i = tid; i < 16 * 64; i += 512) {
    int r = i >> 6, k = i & 63;
    sS[r * 72 + k] = f2bf(A.S[(size_t)(row0 + r) * 64 + k]);
  }
  for (int i = tid; i < 16 * 128; i += 512) {
    int r = i >> 7, k = i & 127;
    sA[0][r * 136 + k] = f2bf(sspf(A.feat_in[(size_t)(row0 + r) * 128 + k]));
  }
  float4v ff;
#pragma unroll
  for (int r = 0; r < 4; ++r)
    ff[r] = A.feat_in[(size_t)(row0 + quad * 4 + r) * 128 + col0];
  if (tid < 16) sE[tid] = 0.0f;
  __syncthreads();

  const float4v Z = {0.f, 0.f, 0.f, 0.f};
  float4v gG, fm, xf, t4;
  float p0 = 0.f, p1 = 0.f, p2 = 0.f, p3 = 0.f, bsum = 0.f;

  // fully unrolled module chain: parity alternates 0,1,0,1,0
  MODBODY(0, 0)
  MODBODY(1, 1)
  MODBODY(2, 0)
  MODBODY(3, 1)
  MODBODY(4, 0)

  // ---- energy reduction (within 16-lane groups, then across 8 c-waves)
#pragma unroll
  for (int o = 1; o < 16; o <<= 1) {
    p0 += __shfl_xor(p0, o, 64);
    p1 += __shfl_xor(p1, o, 64);
    p2 += __shfl_xor(p2, o, 64);
    p3 += __shfl_xor(p3, o, 64);
  }
  if (l16 == 0) {
    atomicAdd(&sE[quad * 4 + 0], p0);
    atomicAdd(&sE[quad * 4 + 1], p1);
    atomicAdd(&sE[quad * 4 + 2], p2);
    atomicAdd(&sE[quad * 4 + 3], p3);
  }
  BAR();
  if (tid < 16) A.energy[row0 + tid] = sE[tid] + bsum;
}

// ---------------------------------------------------------------------------
extern "C" void kernel_launch(void* const* d_in, const int* in_sizes, int n_in,
                              void* d_out, int out_size, void* d_ws, size_t ws_size,
                              hipStream_t stream) {
  const float* features = (const float*)d_in[1];
  const float* radial   = (const float*)d_in[2];
  const int*   idx12    = (const int*)  d_in[3];
  const float* W_I    = (const float*)d_in[4];
  const float* b_I    = (const float*)d_in[5];
  const float* W_J    = (const float*)d_in[6];
  const float* b_J    = (const float*)d_in[7];
  const float* W_gate = (const float*)d_in[8];
  const float* gvec   = (const float*)d_in[9];
  const float* W_int  = (const float*)d_in[10];
  const float* b_int  = (const float*)d_in[11];
  const float* ri_W1  = (const float*)d_in[12];
  const float* ri_b1  = (const float*)d_in[13];
  const float* ri_W2  = (const float*)d_in[14];
  const float* ri_b2  = (const float*)d_in[15];
  const float* ra_W1  = (const float*)d_in[16];
  const float* ra_b1  = (const float*)d_in[17];
  const float* ra_W2  = (const float*)d_in[18];
  const float* ra_b2  = (const float*)d_in[19];
  const float* ro_W1  = (const float*)d_in[20];
  const float* ro_b1  = (const float*)d_in[21];
  const float* ro_W2  = (const float*)d_in[22];
  const float* ro_b2  = (const float*)d_in[23];
  const float* W_out  = (const float*)d_in[24];
  const float* b_out  = (const float*)d_in[25];

  const int N = in_sizes[1] / 128;   // 8192
  const int P = in_sizes[3] / 2;     // 400000
  const int L = in_sizes[25];        // 5
  const int n2p = 2 * P;
  const int C = (n2p + NB - 1) / NB;

  // ws layout: S | bias_pack | Wt | H | tot | off | pairid
  float* S = (float*)d_ws;
  float* bias_pack = S + (size_t)N * 64;
  unsigned short* Wt = (unsigned short*)(bias_pack + 5 * 2304);
  unsigned int* H      = (unsigned int*)(Wt + (size_t)80 * 16384);
  unsigned int* tot    = H + (size_t)NB * 8192;
  unsigned int* off    = tot + N;
  unsigned int* pairid = off + N + 4;

  // ---- K1: fused weight prep + bias pack + hist
  K1Args k1;
  for (int l = 0; l < L; ++l) {
    const float* fx[16] = {
      W_gate + l * 8192,
      W_J + l * 16384, W_I + l * 16384,
      ri_W1 + (l * 3 + 0) * 16384, ri_W2 + (l * 3 + 0) * 16384,
      ri_W1 + (l * 3 + 1) * 16384, ri_W2 + (l * 3 + 1) * 16384,
      ri_W1 + (l * 3 + 2) * 16384, ri_W2 + (l * 3 + 2) * 16384,
      W_int + l * 16384,
      ra_W1 + (l * 2 + 0) * 16384, ra_W2 + (l * 2 + 0) * 16384,
      ra_W1 + (l * 2 + 1) * 16384, ra_W2 + (l * 2 + 1) * 16384,
      ro_W1 + l * 16384, ro_W2 + l * 16384 };
    for (int t = 0; t < 16; ++t) { k1.wsrc[l * 16 + t] = fx[t]; k1.isgate[l * 16 + t] = (t == 0); }
  }
  const float* bp[17] = { b_J, b_I,
    ri_b1, ri_b2, ri_b1 + 128, ri_b2 + 128, ri_b1 + 256, ri_b2 + 256,
    b_int, ra_b1, ra_b2, ra_b1 + 128, ra_b2 + 128, ro_b1, ro_b2, gvec, W_out };
  int st[17] = {128,128, 384,384,384,384,384,384, 128, 256,256,256,256, 128,128,128,128};
  for (int q = 0; q < 17; ++q) { k1.bp[q] = bp[q]; k1.bstride[q] = st[q]; }
  k1.b_out = b_out;
  k1.idx = idx12; k1.Wt = Wt; k1.bias_pack = bias_pack; k1.H = H;
  k1.n2p = n2p; k1.C = C;
  k1_prep<<<80 + 5 + NB, 256, 0, stream>>>(k1);

  // ---- S via LDS-hist sort + gather (no global atomics)
  col_scan<<<32, 256, 0, stream>>>(H, tot);
  place_pass<<<NB, 256, 0, stream>>>(idx12, H, tot, off, pairid, P, C);
  gather_kernel<<<N, 256, 0, stream>>>(radial, off, pairid, S);

  // ---- fused 5-module chain: 512 blocks x 512 threads, 2 blocks/CU
  ChainArgs ca;
  ca.feat_in   = features;
  ca.S         = S;
  ca.wt        = Wt;
  ca.bias_pack = bias_pack;
  ca.energy    = (float*)d_out;
  ca.feat_out  = (float*)d_out + N;
  chain_kernel<<<N / 16, 512, 0, stream>>>(ca);
}

// Round 8
// 316.049 us; speedup vs baseline: 2.3674x; 1.0149x over previous
//
#include <hip/hip_runtime.h>

// ---------------------------------------------------------------------------
// PhysNet stack, MI355X.  v8b = v8 with compile fix (exp2f/log2f, not
// __exp2f/__log2f which don't exist as device intrinsics):
//  - sspf in native exp2/log2 domain (abs/neg folded into input modifiers).
//  - WSSPM: v_cvt_pk_bf16_f32 packs 2 floats/inst; lo/hi-16 store pattern.
//  - col_scan: 256 blocks x 256 thr (32 cols/block, 8-seg LDS scan).
//  - chain structure from v7: 512x512, 2 blocks/CU, reg weights W[2][4],
//    raw s_barrier+lgkmcnt, fully unrolled modules, bias-as-acc-init.
// ---------------------------------------------------------------------------

#define LN2F 0.69314718055994530942f
#define L2EF 1.44269504088896340736f
#define NB 128   // sort blocks

using short8  = __attribute__((ext_vector_type(8))) short;
using float4v = __attribute__((ext_vector_type(4))) float;

__device__ __forceinline__ float sspf(float x) {
  // softplus(x) - ln2 = max(x,0) + LN2*(log2(1 + 2^(-log2e*|x|)) - 1)
  float t = exp2f(-L2EF * fabsf(x));             // v_mul (abs+neg mods) + v_exp
  float l = log2f(1.0f + t);                     // v_add + v_log
  return fmaxf(x, 0.0f) + fmaf(LN2F, l, -LN2F);  // v_max + v_fma
}

__device__ __forceinline__ unsigned short f2bf(float x) {
  return (unsigned short)((__float_as_uint(x) + 0x8000u) >> 16);  // RTN, <=0.5ulp
}

__device__ __forceinline__ unsigned short f2bf_ne(float x) {  // RTNE for weight prep
  unsigned int u = __float_as_uint(x);
  u += 0x7fffu + ((u >> 16) & 1u);
  return (unsigned short)(u >> 16);
}

// ---------------------------------------------------------------------------
// K1: fused prep_weights (blocks 0..79) + pack_bias (80..84) + hist (85..212)
// Weight pack layout (non-gate slot, 16384 shorts):
//   chunk(c,m,lane): offset c*2048 + m*512 + lane*8; lane=(quad,l16);
//   holds W[k = 8*(4m+quad)+kk][n = 16c+l16], kk=0..7.   (gate: c*1024+m*512)
// ---------------------------------------------------------------------------
struct K1Args {
  const float* wsrc[80];
  int isgate[80];
  const float* bp[17];
  int bstride[17];
  const float* b_out;
  const int* idx;
  unsigned short* Wt;
  float* bias_pack;
  unsigned int* H;
  int n2p, C;
};

__global__ __launch_bounds__(256) void k1_prep(K1Args K) {
  __shared__ unsigned int h[8192];
  int b = blockIdx.x, tid = threadIdx.x;
  if (b < 80) {
    const float* s = K.wsrc[b];
    unsigned short* d = K.Wt + (size_t)b * 16384;
    if (!K.isgate[b]) {
      for (int it = 0; it < 8; ++it) {
        int id = tid + it * 256;
        int lane = id & 63, mm = (id >> 6) & 3, c8 = id >> 8;
        int l16 = lane & 15, quad = lane >> 4;
        int n = 16 * c8 + l16, k0 = 8 * (4 * mm + quad);
        unsigned short tmp[8];
#pragma unroll
        for (int cc = 0; cc < 8; ++cc) tmp[cc] = f2bf_ne(s[(k0 + cc) * 128 + n]);
        *(uint4*)(d + c8 * 2048 + mm * 512 + lane * 8) = *(uint4*)tmp;
      }
    } else {
      for (int it = 0; it < 4; ++it) {
        int id = tid + it * 256;                 // 0..1023
        int lane = id & 63, mm = (id >> 6) & 1, c8 = id >> 7;
        int l16 = lane & 15, quad = lane >> 4;
        int n = 16 * c8 + l16, k0 = 8 * (4 * mm + quad);
        unsigned short tmp[8];
#pragma unroll
        for (int cc = 0; cc < 8; ++cc) tmp[cc] = f2bf_ne(s[(k0 + cc) * 128 + n]);
        *(uint4*)(d + c8 * 1024 + mm * 512 + lane * 8) = *(uint4*)tmp;
      }
    }
  } else if (b < 85) {
    int l = b - 80;
    for (int i = tid; i < 17 * 128; i += 256) {
      int s = i >> 7;
      K.bias_pack[(size_t)l * 2304 + i] = K.bp[s][l * K.bstride[s] + (i & 127)];
    }
    if (tid == 0) K.bias_pack[(size_t)l * 2304 + 17 * 128] = K.b_out[l];
  } else {
    int blk = b - 85;
    for (int i = tid; i < 8192; i += 256) h[i] = 0;
    __syncthreads();
    int s = blk * K.C, e = min(s + K.C, K.n2p);
    for (int i = s + tid; i < e; i += 256) atomicAdd(&h[K.idx[i]], 1u);
    __syncthreads();
    for (int i = tid; i < 8192; i += 256) K.H[(size_t)blk * 8192 + i] = h[i];
  }
}

// col_scan v2: 256 blocks x 256 threads; block handles 32 cols; thread
// (r8,c) scans rows r8*16..+16 of col c with an 8-segment LDS prefix.
__global__ __launch_bounds__(256) void col_scan(unsigned int* __restrict__ H,
                                                unsigned int* __restrict__ tot) {
  __shared__ unsigned int part[8][33];
  int c = threadIdx.x & 31, r8 = threadIdx.x >> 5;
  int col = blockIdx.x * 32 + c;
  unsigned int psum = 0;
#pragma unroll 4
  for (int r = r8 * 16; r < r8 * 16 + 16; ++r)
    psum += H[(size_t)r * 8192 + col];
  part[r8][c] = psum;
  __syncthreads();
  if (threadIdx.x < 32) {
    unsigned int run = 0;
#pragma unroll
    for (int s = 0; s < 8; ++s) {
      unsigned int v = part[s][threadIdx.x];
      part[s][threadIdx.x] = run;
      run += v;
    }
    tot[blockIdx.x * 32 + threadIdx.x] = run;
  }
  __syncthreads();
  unsigned int run = part[r8][c];
#pragma unroll 4
  for (int r = r8 * 16; r < r8 * 16 + 16; ++r) {
    unsigned int v = H[(size_t)r * 8192 + col];
    H[(size_t)r * 8192 + col] = run;
    run += v;
  }
}

// place with inline scan of tot (each block redundantly; block 0 publishes off)
__global__ __launch_bounds__(256) void place_pass(const int* __restrict__ idx,
                                                  const unsigned int* __restrict__ H,
                                                  const unsigned int* __restrict__ tot,
                                                  unsigned int* __restrict__ off_out,
                                                  unsigned int* __restrict__ pairid,
                                                  int P, int C) {
  __shared__ unsigned int pos[8192];
  __shared__ unsigned int wt4[4];
  int b = blockIdx.x, tid = threadIdx.x;
  unsigned int local[32], s = 0;
#pragma unroll
  for (int i = 0; i < 32; ++i) { local[i] = tot[tid * 32 + i]; s += local[i]; }
  unsigned int v = s;
  int lane = tid & 63, wv = tid >> 6;
#pragma unroll
  for (int o = 1; o < 64; o <<= 1) {
    unsigned int u = __shfl_up(v, o, 64);
    if (lane >= o) v += u;
  }
  if (lane == 63) wt4[wv] = v;
  __syncthreads();
  unsigned int base = 0;
  for (int k = 0; k < wv; ++k) base += wt4[k];
  unsigned int excl = base + v - s;
#pragma unroll
  for (int i = 0; i < 32; ++i) {
    pos[tid * 32 + i] = excl;
    if (b == 0) off_out[tid * 32 + i] = excl;
    excl += local[i];
  }
  if (b == 0 && tid == 255) off_out[8192] = excl;
  __syncthreads();
  for (int i = tid; i < 8192; i += 256) pos[i] += H[(size_t)b * 8192 + i];
  __syncthreads();
  int n2p = 2 * P;
  int s2 = b * C, e2 = min(s2 + C, n2p);
  for (int i = s2 + tid; i < e2; i += 256) {
    int a = idx[i];
    unsigned int p = atomicAdd(&pos[a], 1u);
    pairid[p] = (i >= P) ? (unsigned int)(i - P) : (unsigned int)i;
  }
}

// Gather: 16-lane group reads a full 256B radial row via dwordx4
__global__ __launch_bounds__(256) void gather_kernel(const float* __restrict__ radial,
                                                     const unsigned int* __restrict__ off,
                                                     const unsigned int* __restrict__ pairid,
                                                     float* __restrict__ S) {
  __shared__ float4v red[3][16];
  int a = blockIdx.x;
  int lane = threadIdx.x & 63, w = threadIdx.x >> 6;
  int grp = lane >> 4, l16v = lane & 15;
  unsigned int b = off[a], e = off[a + 1];
  float4v acc = {0.f, 0.f, 0.f, 0.f};
  for (unsigned int base = b; base < e; base += 128) {
    unsigned int pp[8];
#pragma unroll
    for (int k = 0; k < 8; ++k) {
      unsigned int j = base + k * 16 + w * 4 + grp;
      pp[k] = pairid[j < e ? j : b];          // clamped: always valid
    }
    float4v vv[8];
#pragma unroll
    for (int k = 0; k < 8; ++k)
      vv[k] = *(const float4v*)(radial + (size_t)pp[k] * 64 + l16v * 4);
#pragma unroll
    for (int k = 0; k < 8; ++k) {
      unsigned int j = base + k * 16 + w * 4 + grp;
      if (j < e) acc += vv[k];
    }
  }
#pragma unroll
  for (int o = 16; o < 64; o <<= 1) {
#pragma unroll
    for (int cc = 0; cc < 4; ++cc) acc[cc] += __shfl_xor(acc[cc], o, 64);
  }
  if (w > 0 && grp == 0) red[w - 1][l16v] = acc;
  __syncthreads();
  if (w == 0 && grp == 0) {
    acc += red[0][l16v];
    acc += red[1][l16v];
    acc += red[2][l16v];
    *(float4v*)(S + (size_t)a * 64 + l16v * 4) = acc;
  }
}

// ---------------------------------------------------------------------------
// Chain v8: 512 blocks x 512 threads (8 waves), 2 blocks/CU, 4 waves/EU.
// Weights in registers; modules fully unrolled; acc init = bias; packed cvt.
// ---------------------------------------------------------------------------
struct ChainArgs {
  const float* feat_in;
  const float* S;
  const unsigned short* wt;      // 80 slots x 16384 shorts (fragment order)
  const float* bias_pack;        // 5 x 2304 floats
  float* feat_out;
  float* energy;
};

#define MFMA_ __builtin_amdgcn_mfma_f32_16x16x32_bf16
#define APOFF 2176   // shorts between sA[0] and sA[1] (16*136)

#define BAR() { __builtin_amdgcn_sched_barrier(0); \
  asm volatile("s_waitcnt lgkmcnt(0)" ::: "memory"); \
  __builtin_amdgcn_s_barrier(); \
  __builtin_amdgcn_sched_barrier(0); }

#define LDW(WP, sp) { \
  const unsigned short* wp_ = (sp) + woff; \
  W[WP][0] = *(const short8*)(wp_); \
  W[WP][1] = *(const short8*)(wp_ + 512); \
  W[WP][2] = *(const short8*)(wp_ + 1024); \
  W[WP][3] = *(const short8*)(wp_ + 1536); }

#define BINI(ACC, B) { (ACC)[0] = (B); (ACC)[1] = (B); (ACC)[2] = (B); (ACC)[3] = (B); }

#define G128R(AP, WP, ACC) { \
  short8 a0_ = *(const short8*)(aB + (AP)*APOFF); \
  short8 a1_ = *(const short8*)(aB + (AP)*APOFF + 32); \
  short8 a2_ = *(const short8*)(aB + (AP)*APOFF + 64); \
  short8 a3_ = *(const short8*)(aB + (AP)*APOFF + 96); \
  ACC = MFMA_(a0_, W[WP][0], ACC, 0, 0, 0); \
  ACC = MFMA_(a1_, W[WP][1], ACC, 0, 0, 0); \
  ACC = MFMA_(a2_, W[WP][2], ACC, 0, 0, 0); \
  ACC = MFMA_(a3_, W[WP][3], ACC, 0, 0, 0); }

// packed ssp->bf16 epilogue: 2x v_cvt_pk_bf16_f32 + lo/hi-16 stores
#define WSSPM(AP, V) { \
  float s0_ = sspf((V)[0]), s1_ = sspf((V)[1]); \
  float s2_ = sspf((V)[2]), s3_ = sspf((V)[3]); \
  unsigned int p01_, p23_; \
  asm("v_cvt_pk_bf16_f32 %0, %1, %2" : "=v"(p01_) : "v"(s0_), "v"(s1_)); \
  asm("v_cvt_pk_bf16_f32 %0, %1, %2" : "=v"(p23_) : "v"(s2_), "v"(s3_)); \
  wB[(AP)*APOFF]       = (unsigned short)p01_; \
  wB[(AP)*APOFF + 136] = (unsigned short)(p01_ >> 16); \
  wB[(AP)*APOFF + 272] = (unsigned short)p23_; \
  wB[(AP)*APOFF + 408] = (unsigned short)(p23_ >> 16); }

// Module body; L = module index (0..4), S0 = W-parity of G1's use-buffer.
// Both LITERALS -> all indices compile-time. Biases preloaded into bW[].
#define MODBODY(L, S0) { \
  const float* bp = A.bias_pack + (L) * 2304; \
  const unsigned short* wtp = A.wt + (size_t)(L) * 16 * 16384; \
  float bW[15]; \
  _Pragma("unroll") \
  for (int q = 0; q < 15; ++q) bW[q] = bp[q * 128 + col0]; \
  float gvv = bp[15 * 128 + col0], wvv = bp[16 * 128 + col0]; \
  /* G1: gate + W_J -> fm ; load W_I. (no LDS write -> no barrier) */ \
  { LDW((S0)^1, wtp + 2*16384); \
    gG = Z; \
    { short8 s0_ = *(const short8*)(aS); short8 s1_ = *(const short8*)(aS + 32); \
      gG = MFMA_(s0_, GT0, gG, 0, 0, 0); \
      gG = MFMA_(s1_, GT1, gG, 0, 0, 0); } \
    BINI(fm, bW[0]); G128R(0, (S0), fm); \
    for (int r = 0; r < 4; ++r) fm[r] = sspf(fm[r]); } \
  /* G2: W_I -> proto -> A1 ; load ri1a; prefetch next gate */ \
  { LDW((S0), wtp + 3*16384); \
    if ((L) < 4) { \
      GT0 = *(const short8*)(wtp + 16*16384 + goff); \
      GT1 = *(const short8*)(wtp + 16*16384 + goff + 512); \
    } \
    BINI(t4, bW[1]); G128R(0, (S0)^1, t4); \
    for (int r = 0; r < 4; ++r) xf[r] = fm[r] * gG[r] + sspf(t4[r]); } \
  WSSPM(1, xf); BAR(); \
  /* G3..G8: ri x3 */ \
  { LDW((S0)^1, wtp + 4*16384); BINI(t4, bW[2]); G128R(1, (S0), t4); } \
  WSSPM(0, t4); BAR(); \
  { LDW((S0), wtp + 5*16384); BINI(t4, bW[3]); G128R(0, (S0)^1, t4); \
    for (int r = 0; r < 4; ++r) xf[r] += t4[r]; } \
  WSSPM(1, xf); BAR(); \
  { LDW((S0)^1, wtp + 6*16384); BINI(t4, bW[4]); G128R(1, (S0), t4); } \
  WSSPM(0, t4); BAR(); \
  { LDW((S0), wtp + 7*16384); BINI(t4, bW[5]); G128R(0, (S0)^1, t4); \
    for (int r = 0; r < 4; ++r) xf[r] += t4[r]; } \
  WSSPM(1, xf); BAR(); \
  { LDW((S0)^1, wtp + 8*16384); BINI(t4, bW[6]); G128R(1, (S0), t4); } \
  WSSPM(0, t4); BAR(); \
  { LDW((S0), wtp + 9*16384); BINI(t4, bW[7]); G128R(0, (S0)^1, t4); \
    for (int r = 0; r < 4; ++r) xf[r] += t4[r]; } \
  WSSPM(1, xf); BAR(); \
  /* G9: W_int */ \
  { LDW((S0)^1, wtp + 10*16384); BINI(t4, bW[8]); G128R(1, (S0), t4); \
    for (int r = 0; r < 4; ++r) xf[r] = ff[r] * gvv + t4[r]; } \
  WSSPM(0, xf); BAR(); \
  /* G10..G13: ra x2 */ \
  { LDW((S0), wtp + 11*16384); BINI(t4, bW[9]); G128R(0, (S0)^1, t4); } \
  WSSPM(1, t4); BAR(); \
  { LDW((S0)^1, wtp + 12*16384); BINI(t4, bW[10]); G128R(1, (S0), t4); \
    for (int r = 0; r < 4; ++r) xf[r] += t4[r]; } \
  WSSPM(0, xf); BAR(); \
  { LDW((S0), wtp + 13*16384); BINI(t4, bW[11]); G128R(0, (S0)^1, t4); } \
  WSSPM(1, t4); BAR(); \
  { LDW((S0)^1, wtp + 14*16384); BINI(t4, bW[12]); G128R(1, (S0), t4); \
    for (int r = 0; r < 4; ++r) xf[r] += t4[r]; } \
  WSSPM(0, xf); BAR(); \
  ff = xf; \
  if ((L) == 4) { \
    for (int r = 0; r < 4; ++r) \
      A.feat_out[(size_t)(row0 + quad*4 + r) * 128 + col0] = xf[r]; \
  } \
  /* G14: ro1 */ \
  { LDW((S0), wtp + 15*16384); BINI(t4, bW[13]); G128R(0, (S0)^1, t4); } \
  WSSPM(1, t4); BAR(); \
  /* G15: ro2 + energy ; load next module's W_J */ \
  { if ((L) < 4) LDW((S0)^1, wtp + 17*16384); \
    BINI(t4, bW[14]); G128R(1, (S0), t4); \
    p0 += sspf(xf[0] + t4[0]) * wvv; \
    p1 += sspf(xf[1] + t4[1]) * wvv; \
    p2 += sspf(xf[2] + t4[2]) * wvv; \
    p3 += sspf(xf[3] + t4[3]) * wvv; } \
  bsum += bp[17*128]; \
  BAR(); }

__global__ __launch_bounds__(512)
__attribute__((amdgpu_waves_per_eu(4, 4)))
void chain_kernel(ChainArgs A) {
  __shared__ __align__(16) unsigned short sA[2][16 * 136]; // 8.7 KB
  __shared__ __align__(16) unsigned short sS[16 * 72];     // 2.25 KB
  __shared__ float sE[16];

  const int tid  = threadIdx.x;
  const int row0 = blockIdx.x * 16;
  const int lane = tid & 63;
  const int c    = tid >> 6;       // 0..7 = col 16-chunk
  const int l16  = lane & 15;
  const int quad = lane >> 4;
  const int col0 = 16 * c + l16;

  const int woff = c * 2048 + lane * 8;   // shorts, non-gate slots
  const int goff = c * 1024 + lane * 8;   // shorts, gate slots

  // thread-invariant LDS addresses
  const unsigned short* aB = &sA[0][0] + l16 * 136 + quad * 8;
  unsigned short*       wB = &sA[0][0] + (quad * 4) * 136 + col0;
  const unsigned short* aS = &sS[0] + l16 * 72 + quad * 8;

  // prologue: gate(mod0) + W_J(slot1) into registers
  short8 GT0, GT1;
  short8 W[2][4];
  GT0 = *(const short8*)(A.wt + goff);
  GT1 = *(const short8*)(A.wt + goff + 512);
  LDW(0, A.wt + 16384);

  for (int i = tid; i < 16 * 64; i += 512) {
    int r = i >> 6, k = i & 63;
    sS[r * 72 + k] = f2bf(A.S[(size_t)(row0 + r) * 64 + k]);
  }
  for (int i = tid; i < 16 * 128; i += 512) {
    int r = i >> 7, k = i & 127;
    sA[0][r * 136 + k] = f2bf(sspf(A.feat_in[(size_t)(row0 + r) * 128 + k]));
  }
  float4v ff;
#pragma unroll
  for (int r = 0; r < 4; ++r)
    ff[r] = A.feat_in[(size_t)(row0 + quad * 4 + r) * 128 + col0];
  if (tid < 16) sE[tid] = 0.0f;
  __syncthreads();

  const float4v Z = {0.f, 0.f, 0.f, 0.f};
  float4v gG, fm, xf, t4;
  float p0 = 0.f, p1 = 0.f, p2 = 0.f, p3 = 0.f, bsum = 0.f;

  // fully unrolled module chain: parity alternates 0,1,0,1,0
  MODBODY(0, 0)
  MODBODY(1, 1)
  MODBODY(2, 0)
  MODBODY(3, 1)
  MODBODY(4, 0)

  // ---- energy reduction (within 16-lane groups, then across 8 c-waves)
#pragma unroll
  for (int o = 1; o < 16; o <<= 1) {
    p0 += __shfl_xor(p0, o, 64);
    p1 += __shfl_xor(p1, o, 64);
    p2 += __shfl_xor(p2, o, 64);
    p3 += __shfl_xor(p3, o, 64);
  }
  if (l16 == 0) {
    atomicAdd(&sE[quad * 4 + 0], p0);
    atomicAdd(&sE[quad * 4 + 1], p1);
    atomicAdd(&sE[quad * 4 + 2], p2);
    atomicAdd(&sE[quad * 4 + 3], p3);
  }
  BAR();
  if (tid < 16) A.energy[row0 + tid] = sE[tid] + bsum;
}

// ---------------------------------------------------------------------------
extern "C" void kernel_launch(void* const* d_in, const int* in_sizes, int n_in,
                              void* d_out, int out_size, void* d_ws, size_t ws_size,
                              hipStream_t stream) {
  const float* features = (const float*)d_in[1];
  const float* radial   = (const float*)d_in[2];
  const int*   idx12    = (const int*)  d_in[3];
  const float* W_I    = (const float*)d_in[4];
  const float* b_I    = (const float*)d_in[5];
  const float* W_J    = (const float*)d_in[6];
  const float* b_J    = (const float*)d_in[7];
  const float* W_gate = (const float*)d_in[8];
  const float* gvec   = (const float*)d_in[9];
  const float* W_int  = (const float*)d_in[10];
  const float* b_int  = (const float*)d_in[11];
  const float* ri_W1  = (const float*)d_in[12];
  const float* ri_b1  = (const float*)d_in[13];
  const float* ri_W2  = (const float*)d_in[14];
  const float* ri_b2  = (const float*)d_in[15];
  const float* ra_W1  = (const float*)d_in[16];
  const float* ra_b1  = (const float*)d_in[17];
  const float* ra_W2  = (const float*)d_in[18];
  const float* ra_b2  = (const float*)d_in[19];
  const float* ro_W1  = (const float*)d_in[20];
  const float* ro_b1  = (const float*)d_in[21];
  const float* ro_W2  = (const float*)d_in[22];
  const float* ro_b2  = (const float*)d_in[23];
  const float* W_out  = (const float*)d_in[24];
  const float* b_out  = (const float*)d_in[25];

  const int N = in_sizes[1] / 128;   // 8192
  const int P = in_sizes[3] / 2;     // 400000
  const int L = in_sizes[25];        // 5
  const int n2p = 2 * P;
  const int C = (n2p + NB - 1) / NB;

  // ws layout: S | bias_pack | Wt | H | tot | off | pairid
  float* S = (float*)d_ws;
  float* bias_pack = S + (size_t)N * 64;
  unsigned short* Wt = (unsigned short*)(bias_pack + 5 * 2304);
  unsigned int* H      = (unsigned int*)(Wt + (size_t)80 * 16384);
  unsigned int* tot    = H + (size_t)NB * 8192;
  unsigned int* off    = tot + N;
  unsigned int* pairid = off + N + 4;

  // ---- K1: fused weight prep + bias pack + hist
  K1Args k1;
  for (int l = 0; l < L; ++l) {
    const float* fx[16] = {
      W_gate + l * 8192,
      W_J + l * 16384, W_I + l * 16384,
      ri_W1 + (l * 3 + 0) * 16384, ri_W2 + (l * 3 + 0) * 16384,
      ri_W1 + (l * 3 + 1) * 16384, ri_W2 + (l * 3 + 1) * 16384,
      ri_W1 + (l * 3 + 2) * 16384, ri_W2 + (l * 3 + 2) * 16384,
      W_int + l * 16384,
      ra_W1 + (l * 2 + 0) * 16384, ra_W2 + (l * 2 + 0) * 16384,
      ra_W1 + (l * 2 + 1) * 16384, ra_W2 + (l * 2 + 1) * 16384,
      ro_W1 + l * 16384, ro_W2 + l * 16384 };
    for (int t = 0; t < 16; ++t) { k1.wsrc[l * 16 + t] = fx[t]; k1.isgate[l * 16 + t] = (t == 0); }
  }
  const float* bp[17] = { b_J, b_I,
    ri_b1, ri_b2, ri_b1 + 128, ri_b2 + 128, ri_b1 + 256, ri_b2 + 256,
    b_int, ra_b1, ra_b2, ra_b1 + 128, ra_b2 + 128, ro_b1, ro_b2, gvec, W_out };
  int st[17] = {128,128, 384,384,384,384,384,384, 128, 256,256,256,256, 128,128,128,128};
  for (int q = 0; q < 17; ++q) { k1.bp[q] = bp[q]; k1.bstride[q] = st[q]; }
  k1.b_out = b_out;
  k1.idx = idx12; k1.Wt = Wt; k1.bias_pack = bias_pack; k1.H = H;
  k1.n2p = n2p; k1.C = C;
  k1_prep<<<80 + 5 + NB, 256, 0, stream>>>(k1);

  // ---- S via LDS-hist sort + gather (no global atomics)
  col_scan<<<256, 256, 0, stream>>>(H, tot);
  place_pass<<<NB, 256, 0, stream>>>(idx12, H, tot, off, pairid, P, C);
  gather_kernel<<<N, 256, 0, stream>>>(radial, off, pairid, S);

  // ---- fused 5-module chain: 512 blocks x 512 threads, 2 blocks/CU
  ChainArgs ca;
  ca.feat_in   = features;
  ca.S         = S;
  ca.wt        = Wt;
  ca.bias_pack = bias_pack;
  ca.energy    = (float*)d_out;
  ca.feat_out  = (float*)d_out + N;
  chain_kernel<<<N / 16, 512, 0, stream>>>(ca);
}